// Round 13
// baseline (162.746 us; speedup 1.0000x reference)
//
#include <hip/hip_runtime.h>
#include <math.h>

typedef _Float16 f16;
typedef _Float16 f16x4 __attribute__((ext_vector_type(4)));
typedef _Float16 f16x8 __attribute__((ext_vector_type(8)));
typedef float f32x4 __attribute__((ext_vector_type(4)));

#define S_TOTAL 16384
#define N_NODES 512
#define N_PIPES 1024
#define N_DEM   256
#define HIDDEN  64
#define T_SCALE 256.0f

#define MFMA16(a, b, c) __builtin_amdgcn_mfma_f32_16x16x32_f16(a, b, c, 0, 0, 0)

// ================= fused prep: MLP + transposes + conversions + gathers ========
__global__ __launch_bounds__(256) void prep_all(
    const float* __restrict__ W1, const float* __restrict__ b1,
    const float* __restrict__ W2, const float* __restrict__ b2,
    const float* __restrict__ W3, const float* __restrict__ b3,
    const float* __restrict__ base,
    const float* __restrict__ L, const float* __restrict__ dpipe,
    const float* __restrict__ Cw,
    const float* __restrict__ Mf, const float* __restrict__ inv,
    const float* __restrict__ A0, const float* __restrict__ D,
    const int* __restrict__ dmap,
    float* __restrict__ net, float* __restrict__ lKc,
    f16* __restrict__ MT16, f16* __restrict__ invT16,
    f16* __restrict__ inv16, f16* __restrict__ A016, f16* __restrict__ D16,
    f16* __restrict__ DI16, f16* __restrict__ IDXT,
    float* __restrict__ out, int out_size)
{
    __shared__ __align__(16) f16 tile[64][72];
    const int b = blockIdx.x, t = threadIdx.x;
    if (b < 256) {
        if (b == 0) for (int i = t; i < out_size; i += 256) out[i] = 0.f;
        const int wid = t >> 6, k = t & 63;
        const int p = b * 4 + wid;
        const float x = (float)p;
        float h1 = tanhf(x * W1[k] + b1[k]);
        float acc = b2[k];
        #pragma unroll
        for (int j = 0; j < HIDDEN; ++j) {
            float hj = __shfl(h1, j, 64);
            acc = fmaf(hj, W2[j * HIDDEN + k], acc);
        }
        float partial = tanhf(acc) * W3[k];
        #pragma unroll
        for (int off = 32; off > 0; off >>= 1) partial += __shfl_down(partial, off, 64);
        if (k == 0) {
            net[p] = base[p] + partial + b3[0];
            lKc[p] = log2f(10.667f) - 1.852f * log2f(Cw[p]) - 4.871f * log2f(dpipe[p]) + log2f(L[p]);
        }
        return;
    }
    if (b < 512) {
        const int idx = b - 256;
        const float* in = (idx < 128) ? Mf : inv;
        f16* outp = (idx < 128) ? MT16 : invT16;
        const int i2 = idx & 127;
        const int bx = i2 & 15, by = i2 >> 4;
        const int r0 = by * 64, c0 = bx * 64;
        const int lr = t / 16, lc4 = (t % 16) * 4;
        #pragma unroll
        for (int i = 0; i < 4; ++i) {
            int r = lr + i * 16;
            float4 v = *(const float4*)(in + (size_t)(r0 + r) * N_PIPES + c0 + lc4);
            tile[lc4 + 0][r] = (f16)v.x; tile[lc4 + 1][r] = (f16)v.y;
            tile[lc4 + 2][r] = (f16)v.z; tile[lc4 + 3][r] = (f16)v.w;
        }
        __syncthreads();
        const int wrow = t / 4, wc16 = (t % 4) * 16;
        *(f16x8*)(outp + (size_t)(c0 + wrow) * N_NODES + r0 + wc16)     = *(f16x8*)&tile[wrow][wc16];
        *(f16x8*)(outp + (size_t)(c0 + wrow) * N_NODES + r0 + wc16 + 8) = *(f16x8*)&tile[wrow][wc16 + 8];
        return;
    }
    const int tid = (b - 512) * 256 + t;
    const int np = 768 * 256;
    for (int i = tid; i < (N_NODES * N_PIPES) / 4; i += np) {
        float4 v = ((const float4*)inv)[i];
        ((f16x4*)inv16)[i] = (f16x4){(f16)v.x, (f16)v.y, (f16)v.z, (f16)v.w};
        float4 w = ((const float4*)A0)[i];
        ((f16x4*)A016)[i] = (f16x4){(f16)w.x, (f16)w.y, (f16)w.z, (f16)w.w};
    }
    for (int i = tid; i < (S_TOTAL * N_DEM) / 4; i += np) {
        float4 v = ((const float4*)D)[i];
        ((f16x4*)D16)[i] = (f16x4){(f16)v.x, (f16)v.y, (f16)v.z, (f16)v.w};
    }
    for (int i = tid; i < N_DEM * (N_PIPES / 4); i += np) {
        int j = i >> 8, p0 = (i & 255) * 4;
        float4 v = *(const float4*)(inv + (size_t)dmap[j] * N_PIPES + p0);
        *(f16x4*)(DI16 + (size_t)j * N_PIPES + p0) = (f16x4){(f16)v.x, (f16)v.y, (f16)v.z, (f16)v.w};
    }
    for (int i = tid; i < N_PIPES * (N_DEM / 4); i += np) {
        int p = i >> 6, j0 = (i & 63) * 4;
        f16x4 o;
        #pragma unroll
        for (int u = 0; u < 4; ++u)
            o[u] = (f16)inv[(size_t)dmap[j0 + u] * N_PIPES + p];
        *(f16x4*)(IDXT + (size_t)p * N_DEM + j0) = o;
    }
}

// ---------------- small MFMA GEMM body (256 thr) -------------------------------
struct GemmP {
    const f16* A; int lda;
    const f16* B; int ldb;
    f16* C; int ldc;
    int K;
    const int* dmap;
    int gx, gy;
};

__device__ __forceinline__ void gemm_body(const GemmP& P, int bx, int by) {
    __shared__ __align__(16) f16 As[128][72], Bs[64][72];
    const int m0 = by * 128, c0 = bx * 64;
    const int t = threadIdx.x, lane = t & 63, wid = t >> 6;
    const int wr = wid >> 1, wc = wid & 1;
    const int cl = lane & 15, g = lane >> 4;
    const int tr = t >> 3, tc = (t & 7) * 8;
    f32x4 acc[4][2] = {};
    for (int k0 = 0; k0 < P.K; k0 += 64) {
        #pragma unroll
        for (int r = 0; r < 4; ++r) {
            int row = r * 32 + tr;
            *(f16x8*)&As[row][tc] = *(const f16x8*)(P.A + (size_t)(m0 + row) * P.lda + k0 + tc);
        }
        #pragma unroll
        for (int r = 0; r < 2; ++r) {
            int row = r * 32 + tr;
            *(f16x8*)&Bs[row][tc] = *(const f16x8*)(P.B + (size_t)(c0 + row) * P.ldb + k0 + tc);
        }
        __syncthreads();
        #pragma unroll
        for (int kk = 0; kk < 2; ++kk) {
            const int kb = kk * 32 + g * 8;
            f16x8 a[4], bfr[2];
            #pragma unroll
            for (int m = 0; m < 4; ++m) a[m] = *(const f16x8*)&As[wr * 64 + m * 16 + cl][kb];
            #pragma unroll
            for (int n = 0; n < 2; ++n) bfr[n] = *(const f16x8*)&Bs[wc * 32 + n * 16 + cl][kb];
            #pragma unroll
            for (int m = 0; m < 4; ++m)
                #pragma unroll
                for (int n = 0; n < 2; ++n)
                    acc[m][n] = MFMA16(a[m], bfr[n], acc[m][n]);
        }
        __syncthreads();
    }
    #pragma unroll
    for (int m = 0; m < 4; ++m)
        #pragma unroll
        for (int reg = 0; reg < 4; ++reg) {
            const int row = m0 + wr * 64 + m * 16 + g * 4 + reg;
            #pragma unroll
            for (int n = 0; n < 2; ++n) {
                const int col = c0 + wc * 32 + n * 16 + cl;
                float v = acc[m][n][reg];
                if (P.dmap && P.dmap[col] == row) v -= 1.0f;
                P.C[(size_t)row * P.ldc + col] = (f16)v;
            }
        }
}

__global__ __launch_bounds__(256) void gemm_small3(GemmP p0, GemmP p1, GemmP p2) {
    const GemmP& P = (blockIdx.z == 0) ? p0 : (blockIdx.z == 1) ? p1 : p2;
    if ((int)blockIdx.x >= P.gx || (int)blockIdx.y >= P.gy) return;
    gemm_body(P, blockIdx.x, blockIdx.y);
}

__global__ __launch_bounds__(256) void gemm_small1(GemmP p0) {
    gemm_body(p0, blockIdx.x, blockIdx.y);
}

// ======================= fused qt+res (64s-strip x 512n, 512 thr) ==============
// Per chunk pc (64 pipes): Q: q = Ds*IDXT^T (K=256) -> t in LDS -> H: accH += t*inv^T.
// Then R: accR = Ds*P1p^T (K=256). Epilogue: residual + reduce. t never hits HBM.
// B-operands read directly from global (L2-resident, no reuse within block).
__global__ __launch_bounds__(512, 2) void qtres_fused(
    const f16* __restrict__ D16, const int* __restrict__ leak_id,
    const f16* __restrict__ IDXT, const float* __restrict__ net,
    const f16* __restrict__ G16, const float* __restrict__ lKc,
    const float* __restrict__ supply,
    const f16* __restrict__ inv16, const f16* __restrict__ P1p,
    const f16* __restrict__ MT16, const f16* __restrict__ G2_16,
    const float* __restrict__ Cd_p, const float* __restrict__ a_p,
    float scale, float* __restrict__ out)
{
    __shared__ __align__(16) f16 Ds[64][264];     // D-strip, pad 8 (2-way banks = free)
    __shared__ __align__(16) f16 tq[2][64][72];   // t-chunk dbuf, pad 8
    const int sb = blockIdx.x * 64;
    const int t = threadIdx.x, lane = t & 63, w = t >> 6;
    const int cl = lane & 15, g = lane >> 4;
    const int wq_r = w >> 2, wq_c = w & 3;        // Q-phase: 2x4 waves, wave = 32s x 16p

    // ---- load D-strip (once) ----
    {
        const int row = t >> 3, c0 = (t & 7) * 32;
        const f16* src = D16 + (size_t)(sb + row) * N_DEM + c0;
        #pragma unroll
        for (int u = 0; u < 4; ++u)
            *(f16x8*)&Ds[row][c0 + u * 8] = *(const f16x8*)(src + u * 8);
    }
    // ---- hoist leak idx / net for Q-epilogue rows ----
    int idxQ[2][4]; float nvQ[2][4];
    #pragma unroll
    for (int m = 0; m < 2; ++m)
        #pragma unroll
        for (int reg = 0; reg < 4; ++reg) {
            idxQ[m][reg] = leak_id[sb + 32 * wq_r + m * 16 + g * 4 + reg];
            nvQ[m][reg] = net[idxQ[m][reg]];
        }
    __syncthreads();

    f32x4 accH[4][4] = {}, accR[4][4] = {};

    #pragma unroll 1
    for (int pc = 0; pc < 16; ++pc) {
        const int p0 = pc * 64;
        const int bp = p0 + wq_c * 16 + cl;       // this lane's pipe (Q B-row)
        // ---- Q GEMM: aq = Ds(32s x 256) * IDXT[bp][*] ----
        f32x4 aq0 = {0.f, 0.f, 0.f, 0.f}, aq1 = {0.f, 0.f, 0.f, 0.f};
        #pragma unroll
        for (int ks = 0; ks < 8; ++ks) {
            const int kb = ks * 32 + g * 8;
            f16x8 bq = *(const f16x8*)(IDXT + (size_t)bp * N_DEM + kb);
            f16x8 a0 = *(const f16x8*)&Ds[32 * wq_r + cl][kb];
            f16x8 a1 = *(const f16x8*)&Ds[32 * wq_r + 16 + cl][kb];
            aq0 = MFMA16(a0, bq, aq0);
            aq1 = MFMA16(a1, bq, aq1);
        }
        // ---- T epilogue: t = (supply - hL)/T_SCALE -> tq[pc&1] ----
        {
            const float lk = lKc[bp], sup = supply[bp];
            #pragma unroll
            for (int m = 0; m < 2; ++m) {
                #pragma unroll
                for (int reg = 0; reg < 4; ++reg) {
                    const int srow = 32 * wq_r + m * 16 + g * 4 + reg;
                    float qv = (m ? aq1[reg] : aq0[reg]) +
                               nvQ[m][reg] * (float)G16[(size_t)idxQ[m][reg] * N_PIPES + bp];
                    float l = __builtin_amdgcn_logf(fabsf(qv));
                    float hL = copysignf(__builtin_amdgcn_exp2f(fmaf(1.852f, l, lk)), qv);
                    tq[pc & 1][srow][wq_c * 16 + cl] = (f16)((sup - hL) * (1.0f / T_SCALE));
                }
            }
        }
        __syncthreads();   // tq[pc&1] ready; also fences reuse of tq[(pc-1)&1] readers
        // ---- H GEMM: accH += tq(64 x 64) * inv16[n][p-chunk]; wave n-slice = w*64 ----
        #pragma unroll
        for (int ks = 0; ks < 2; ++ks) {
            const int kb = ks * 32 + g * 8;
            f16x8 bh[4];
            #pragma unroll
            for (int fn = 0; fn < 4; ++fn)
                bh[fn] = *(const f16x8*)(inv16 + (size_t)(w * 64 + fn * 16 + cl) * N_PIPES + p0 + kb);
            #pragma unroll
            for (int m = 0; m < 4; ++m) {
                f16x8 a = *(const f16x8*)&tq[pc & 1][m * 16 + cl][kb];
                #pragma unroll
                for (int fn = 0; fn < 4; ++fn)
                    accH[m][fn] = MFMA16(a, bh[fn], accH[m][fn]);
            }
        }
    }

    // ---- R GEMM: accR = Ds(64 x 256) * P1p[n][*]; wave n-slice = w*64 ----
    #pragma unroll
    for (int ks = 0; ks < 8; ++ks) {
        const int kb = ks * 32 + g * 8;
        f16x8 br[4];
        #pragma unroll
        for (int fn = 0; fn < 4; ++fn)
            br[fn] = *(const f16x8*)(P1p + (size_t)(w * 64 + fn * 16 + cl) * N_DEM + kb);
        #pragma unroll
        for (int m = 0; m < 4; ++m) {
            f16x8 a = *(const f16x8*)&Ds[m * 16 + cl][kb];
            #pragma unroll
            for (int fn = 0; fn < 4; ++fn)
                accR[m][fn] = MFMA16(a, br[fn], accR[m][fn]);
        }
    }

    // ---- final epilogue: residual + square + reduce ----
    const float cda = Cd_p[0] * a_p[0] * sqrtf(2.f * 9.80665f);
    float lsum = 0.f;
    #pragma unroll
    for (int m = 0; m < 4; ++m) {
        #pragma unroll
        for (int reg = 0; reg < 4; ++reg) {
            const int srow = m * 16 + g * 4 + reg;
            const int idx = leak_id[sb + srow];
            const float nv = net[idx];
            #pragma unroll
            for (int fn = 0; fn < 4; ++fn) {
                const int node = w * 64 + fn * 16 + cl;
                const float H = accH[m][fn][reg] * T_SCALE;
                const float sq = (H > 0.f) ? sqrtf(H) : 0.f;
                const float dl = cda * (float)MT16[(size_t)idx * N_NODES + node] * sq;
                const float r = accR[m][fn][reg] + nv * (float)G2_16[(size_t)idx * N_NODES + node] - dl;
                lsum += r * r;
            }
        }
    }
    #pragma unroll
    for (int off = 32; off > 0; off >>= 1) lsum += __shfl_down(lsum, off, 64);
    __syncthreads();                 // all Ds reads done; reuse as scratch
    float* wred = (float*)&Ds[0][0];
    if (lane == 0) wred[w] = lsum;
    __syncthreads();
    if (t == 0) {
        float tot = 0.f;
        #pragma unroll
        for (int i = 0; i < 8; ++i) tot += wred[i];
        atomicAdd(out, tot * scale);
    }
}

extern "C" void kernel_launch(void* const* d_in, const int* in_sizes, int n_in,
                              void* d_out, int out_size, void* d_ws, size_t ws_size,
                              hipStream_t stream) {
    const float* D          = (const float*)d_in[0];
    const int*   leak_id    = (const int*)  d_in[1];
    const float* A0         = (const float*)d_in[2];
    const float* inv        = (const float*)d_in[3];
    const float* M          = (const float*)d_in[4];
    const float* supply     = (const float*)d_in[5];
    const float* L          = (const float*)d_in[6];
    const float* dpipe      = (const float*)d_in[7];
    const float* C          = (const float*)d_in[8];
    const float* a_p        = (const float*)d_in[9];
    const float* Cd_p       = (const float*)d_in[10];
    const float* W1         = (const float*)d_in[11];
    const float* b1         = (const float*)d_in[12];
    const float* W2         = (const float*)d_in[13];
    const float* b2         = (const float*)d_in[14];
    const float* W3         = (const float*)d_in[15];
    const float* b3         = (const float*)d_in[16];
    const float* base       = (const float*)d_in[17];
    const int*   demand_idx = (const int*)  d_in[18];

    char* ws = (char*)d_ws;
    size_t off = 0;
    auto carve = [&](size_t bytes) { char* p = ws + off; off += (bytes + 255) & ~(size_t)255; return p; };
    float* net    = (float*)carve(N_PIPES * 4);
    float* lKc    = (float*)carve(N_PIPES * 4);
    f16* inv16  = (f16*)carve((size_t)N_NODES * N_PIPES * 2);
    f16* A016   = (f16*)carve((size_t)N_NODES * N_PIPES * 2);
    f16* MT16   = (f16*)carve((size_t)N_PIPES * N_NODES * 2);
    f16* invT16 = (f16*)carve((size_t)N_PIPES * N_NODES * 2);
    f16* G16    = (f16*)carve((size_t)N_PIPES * N_PIPES * 2);
    f16* G2_16  = (f16*)carve((size_t)N_PIPES * N_NODES * 2);
    f16* Wt     = (f16*)carve((size_t)N_NODES * N_NODES * 2);
    f16* P1p    = (f16*)carve((size_t)N_NODES * N_DEM * 2);
    f16* DI16   = (f16*)carve((size_t)N_DEM * N_PIPES * 2);
    f16* IDXT   = (f16*)carve((size_t)N_PIPES * N_DEM * 2);
    f16* D16    = (f16*)carve((size_t)S_TOTAL * N_DEM * 2);

    // ---- dispatch 1: all prep (also zeroes d_out) ----
    prep_all<<<1280, 256, 0, stream>>>(
        W1, b1, W2, b2, W3, b3, base, L, dpipe, C,
        M, inv, A0, D, demand_idx,
        net, lKc, MT16, invT16, inv16, A016, D16, DI16, IDXT,
        (float*)d_out, out_size);

    // ---- dispatch 2: three independent small GEMMs ----
    GemmP pG16 = {MT16, N_NODES, invT16, N_NODES, G16, N_PIPES, N_NODES, nullptr, 16, 8};
    GemmP pWt  = {A016, N_PIPES, inv16, N_PIPES, Wt, N_NODES, N_PIPES, nullptr, 8, 4};
    GemmP pP1  = {A016, N_PIPES, DI16, N_PIPES, P1p, N_DEM, N_PIPES, demand_idx, 4, 4};
    gemm_small3<<<dim3(16, 8, 3), 256, 0, stream>>>(pG16, pWt, pP1);

    // ---- dispatch 3: G2 = MT16 * Wt^T (1024x512, K=512) ----
    GemmP pG2 = {MT16, N_NODES, Wt, N_NODES, G2_16, N_NODES, N_NODES, nullptr, 8, 8};
    gemm_small1<<<dim3(8, 8), 256, 0, stream>>>(pG2);

    // ---- dispatch 4: fused qt+res ----
    const float scale = 1.f / ((float)S_TOTAL * (float)N_NODES);
    qtres_fused<<<256, 512, 0, stream>>>(
        D16, leak_id, IDXT, net, G16, lKc, supply,
        inv16, P1p, MT16, G2_16, Cd_p, a_p, scale, (float*)d_out);
}

// Round 14
// 103.875 us; speedup vs baseline: 1.5667x; 1.5667x over previous
//
#include <hip/hip_runtime.h>
#include <math.h>

typedef _Float16 f16;
typedef _Float16 f16x4 __attribute__((ext_vector_type(4)));
typedef _Float16 f16x8 __attribute__((ext_vector_type(8)));
typedef float f32x4 __attribute__((ext_vector_type(4)));

#define S_TOTAL 16384
#define N_NODES 512
#define N_PIPES 1024
#define N_DEM   256
#define HIDDEN  64
#define T_SCALE 256.0f   // t = (supply - hL)/T_SCALE to fit f16 range; H *= T_SCALE

// direct HBM -> LDS, 16B per lane (wave writes base + lane*16, LINEAR dest)
#define GLOAD16(gsrc, ldst) \
    __builtin_amdgcn_global_load_lds((const __attribute__((address_space(1))) void*)(gsrc), \
                                     (__attribute__((address_space(3))) void*)(ldst), 16, 0, 0)
#define SBAR()  __builtin_amdgcn_s_barrier()
#define FENCE() asm volatile("" ::: "memory")
#define WAITN(n) asm volatile("s_waitcnt vmcnt(" #n ")" ::: "memory")

// ================= fused prep: MLP + transposes + conversions + gathers ========
__global__ __launch_bounds__(256) void prep_all(
    const float* __restrict__ W1, const float* __restrict__ b1,
    const float* __restrict__ W2, const float* __restrict__ b2,
    const float* __restrict__ W3, const float* __restrict__ b3,
    const float* __restrict__ base,
    const float* __restrict__ L, const float* __restrict__ dpipe,
    const float* __restrict__ Cw,
    const float* __restrict__ Mf, const float* __restrict__ inv,
    const float* __restrict__ A0, const float* __restrict__ D,
    const int* __restrict__ dmap,
    float* __restrict__ net, float* __restrict__ lKc,
    f16* __restrict__ MT16, f16* __restrict__ invT16,
    f16* __restrict__ inv16, f16* __restrict__ A016, f16* __restrict__ D16,
    f16* __restrict__ DI16, f16* __restrict__ IDXT,
    float* __restrict__ out, int out_size)
{
    __shared__ __align__(16) f16 tile[64][72];
    const int b = blockIdx.x, t = threadIdx.x;
    if (b < 256) {
        if (b == 0) for (int i = t; i < out_size; i += 256) out[i] = 0.f;
        const int wid = t >> 6, k = t & 63;
        const int p = b * 4 + wid;
        const float x = (float)p;
        float h1 = tanhf(x * W1[k] + b1[k]);
        float acc = b2[k];
        #pragma unroll
        for (int j = 0; j < HIDDEN; ++j) {
            float hj = __shfl(h1, j, 64);
            acc = fmaf(hj, W2[j * HIDDEN + k], acc);
        }
        float partial = tanhf(acc) * W3[k];
        #pragma unroll
        for (int off = 32; off > 0; off >>= 1) partial += __shfl_down(partial, off, 64);
        if (k == 0) {
            net[p] = base[p] + partial + b3[0];
            lKc[p] = log2f(10.667f) - 1.852f * log2f(Cw[p]) - 4.871f * log2f(dpipe[p]) + log2f(L[p]);
        }
        return;
    }
    if (b < 512) {
        const int idx = b - 256;
        const float* in = (idx < 128) ? Mf : inv;
        f16* outp = (idx < 128) ? MT16 : invT16;
        const int i2 = idx & 127;
        const int bx = i2 & 15, by = i2 >> 4;
        const int r0 = by * 64, c0 = bx * 64;
        const int lr = t / 16, lc4 = (t % 16) * 4;
        #pragma unroll
        for (int i = 0; i < 4; ++i) {
            int r = lr + i * 16;
            float4 v = *(const float4*)(in + (size_t)(r0 + r) * N_PIPES + c0 + lc4);
            tile[lc4 + 0][r] = (f16)v.x; tile[lc4 + 1][r] = (f16)v.y;
            tile[lc4 + 2][r] = (f16)v.z; tile[lc4 + 3][r] = (f16)v.w;
        }
        __syncthreads();
        const int wrow = t / 4, wc16 = (t % 4) * 16;
        *(f16x8*)(outp + (size_t)(c0 + wrow) * N_NODES + r0 + wc16)     = *(f16x8*)&tile[wrow][wc16];
        *(f16x8*)(outp + (size_t)(c0 + wrow) * N_NODES + r0 + wc16 + 8) = *(f16x8*)&tile[wrow][wc16 + 8];
        return;
    }
    const int tid = (b - 512) * 256 + t;
    const int np = 768 * 256;
    for (int i = tid; i < (N_NODES * N_PIPES) / 4; i += np) {
        float4 v = ((const float4*)inv)[i];
        ((f16x4*)inv16)[i] = (f16x4){(f16)v.x, (f16)v.y, (f16)v.z, (f16)v.w};
        float4 w = ((const float4*)A0)[i];
        ((f16x4*)A016)[i] = (f16x4){(f16)w.x, (f16)w.y, (f16)w.z, (f16)w.w};
    }
    for (int i = tid; i < (S_TOTAL * N_DEM) / 4; i += np) {
        float4 v = ((const float4*)D)[i];
        ((f16x4*)D16)[i] = (f16x4){(f16)v.x, (f16)v.y, (f16)v.z, (f16)v.w};
    }
    for (int i = tid; i < N_DEM * (N_PIPES / 4); i += np) {
        int j = i >> 8, p0 = (i & 255) * 4;
        float4 v = *(const float4*)(inv + (size_t)dmap[j] * N_PIPES + p0);
        *(f16x4*)(DI16 + (size_t)j * N_PIPES + p0) = (f16x4){(f16)v.x, (f16)v.y, (f16)v.z, (f16)v.w};
    }
    for (int i = tid; i < N_PIPES * (N_DEM / 4); i += np) {
        int p = i >> 6, j0 = (i & 63) * 4;
        f16x4 o;
        #pragma unroll
        for (int u = 0; u < 4; ++u)
            o[u] = (f16)inv[(size_t)dmap[j0 + u] * N_PIPES + p];
        *(f16x4*)(IDXT + (size_t)p * N_DEM + j0) = o;
    }
}

// ---------------- small MFMA GEMM body (256 thr) -------------------------------
struct GemmP {
    const f16* A; int lda;
    const f16* B; int ldb;
    f16* C; int ldc;
    int K;
    const int* dmap;
    int gx, gy;
};

__device__ __forceinline__ void gemm_body(const GemmP& P, int bx, int by) {
    __shared__ __align__(16) f16 As[128][72], Bs[64][72];
    const int m0 = by * 128, c0 = bx * 64;
    const int t = threadIdx.x, lane = t & 63, wid = t >> 6;
    const int wr = wid >> 1, wc = wid & 1;
    const int cl = lane & 15, g = lane >> 4;
    const int tr = t >> 3, tc = (t & 7) * 8;
    f32x4 acc[4][2] = {};
    for (int k0 = 0; k0 < P.K; k0 += 64) {
        #pragma unroll
        for (int r = 0; r < 4; ++r) {
            int row = r * 32 + tr;
            *(f16x8*)&As[row][tc] = *(const f16x8*)(P.A + (size_t)(m0 + row) * P.lda + k0 + tc);
        }
        #pragma unroll
        for (int r = 0; r < 2; ++r) {
            int row = r * 32 + tr;
            *(f16x8*)&Bs[row][tc] = *(const f16x8*)(P.B + (size_t)(c0 + row) * P.ldb + k0 + tc);
        }
        __syncthreads();
        #pragma unroll
        for (int kk = 0; kk < 2; ++kk) {
            const int kb = kk * 32 + g * 8;
            f16x8 a[4], bfr[2];
            #pragma unroll
            for (int m = 0; m < 4; ++m) a[m] = *(const f16x8*)&As[wr * 64 + m * 16 + cl][kb];
            #pragma unroll
            for (int n = 0; n < 2; ++n) bfr[n] = *(const f16x8*)&Bs[wc * 32 + n * 16 + cl][kb];
            #pragma unroll
            for (int m = 0; m < 4; ++m)
                #pragma unroll
                for (int n = 0; n < 2; ++n)
                    acc[m][n] = __builtin_amdgcn_mfma_f32_16x16x32_f16(a[m], bfr[n], acc[m][n], 0, 0, 0);
        }
        __syncthreads();
    }
    #pragma unroll
    for (int m = 0; m < 4; ++m)
        #pragma unroll
        for (int reg = 0; reg < 4; ++reg) {
            const int row = m0 + wr * 64 + m * 16 + g * 4 + reg;
            #pragma unroll
            for (int n = 0; n < 2; ++n) {
                const int col = c0 + wc * 32 + n * 16 + cl;
                float v = acc[m][n][reg];
                if (P.dmap && P.dmap[col] == row) v -= 1.0f;
                P.C[(size_t)row * P.ldc + col] = (f16)v;
            }
        }
}

__global__ __launch_bounds__(256) void gemm_small3(GemmP p0, GemmP p1, GemmP p2) {
    const GemmP& P = (blockIdx.z == 0) ? p0 : (blockIdx.z == 1) ? p1 : p2;
    if ((int)blockIdx.x >= P.gx || (int)blockIdx.y >= P.gy) return;
    gemm_body(P, blockIdx.x, blockIdx.y);
}

// ======================= gemm_qt + G2 rider (512 thr) ==========================
// y<128: q[s][p] = D16*IDXT^T + nv*G16[idx]; t = (supply - hL)/T_SCALE
// y>=128: G2[i][c] = sum_k MT16[i][k]*Wt[c][k]  (1024x512, K=512)
__global__ __launch_bounds__(512, 4) void gemm_qt_mfma(
    const f16* __restrict__ D16, const int* __restrict__ leak_id,
    const f16* __restrict__ IDXT, const float* __restrict__ net,
    const f16* __restrict__ G16, const float* __restrict__ lKc,
    const float* __restrict__ supply, f16* __restrict__ t16,
    const f16* __restrict__ MT16, const f16* __restrict__ Wt,
    f16* __restrict__ G2out)
{
    __shared__ __align__(16) f16 As[2][128][64];   // 32 KB
    __shared__ __align__(16) f16 Bs[2][128][64];   // 32 KB
    const int t = threadIdx.x, lane = t & 63, wid = t >> 6;

    if (blockIdx.y >= 128) {     // ---------------- G2 rider ----------------
        f16 (*A2)[72] = (f16(*)[72])&Bs[0][0][0];
        f16 (*B2)[72] = (f16(*)[72])&As[0][0][0];
        const int m0 = ((int)blockIdx.y - 128) * 128, c0 = blockIdx.x * 64;
        const int wr = wid >> 2, wc = wid & 3;
        const int cl = lane & 15, g = lane >> 4;
        f32x4 acc[4] = {};
        for (int k0 = 0; k0 < 512; k0 += 64) {
            {
                int r = t >> 2, c16 = (t & 3) * 16;
                *(f16x8*)&A2[r][c16]     = *(const f16x8*)(MT16 + (size_t)(m0 + r) * N_NODES + k0 + c16);
                *(f16x8*)&A2[r][c16 + 8] = *(const f16x8*)(MT16 + (size_t)(m0 + r) * N_NODES + k0 + c16 + 8);
                int r2 = t >> 3, c8 = (t & 7) * 8;
                *(f16x8*)&B2[r2][c8] = *(const f16x8*)(Wt + (size_t)(c0 + r2) * N_NODES + k0 + c8);
            }
            __syncthreads();
            #pragma unroll
            for (int kk = 0; kk < 2; ++kk) {
                const int kb = kk * 32 + g * 8;
                f16x8 b = *(const f16x8*)&B2[wc * 16 + cl][kb];
                #pragma unroll
                for (int m = 0; m < 4; ++m) {
                    f16x8 a = *(const f16x8*)&A2[wr * 64 + m * 16 + cl][kb];
                    acc[m] = __builtin_amdgcn_mfma_f32_16x16x32_f16(a, b, acc[m], 0, 0, 0);
                }
            }
            __syncthreads();
        }
        #pragma unroll
        for (int m = 0; m < 4; ++m)
            #pragma unroll
            for (int reg = 0; reg < 4; ++reg)
                G2out[(size_t)(m0 + wr * 64 + m * 16 + g * 4 + reg) * N_NODES + c0 + wc * 16 + cl] = (f16)acc[m][reg];
        return;
    }
    // ---------------- qt tiles (round-10/12 schedule, unchanged) ----------------
    const int bid = blockIdx.y * 8 + blockIdx.x;
    const int w = (bid & 7) * 128 + (bid >> 3);
    const int bx = w & 7, by = w >> 3;
    const int p0 = bx * 128, sb = by * 128;
    const int wr = wid >> 2, wc = wid & 3;
    const int cl = lane & 15, g = lane >> 4;
    const int swrow = lane >> 3;
    const int swcol = ((lane & 7) ^ swrow) * 8;
    const int sx0 = (g ^ (cl & 7)) * 8, sx1 = ((4 + g) ^ (cl & 7)) * 8;

    const f16* Abase = D16 + (size_t)(sb + swrow) * N_DEM + swcol;
    const f16* Bbase = IDXT + (size_t)(p0 + swrow) * N_DEM + swcol;

    f32x4 acc[4][2] = {};
    auto stage = [&](int buf, int k0) {
        #pragma unroll
        for (int c = 0; c < 2; ++c) {
            int r0 = c * 64 + wid * 8;
            GLOAD16(Abase + (size_t)r0 * N_DEM + k0, &As[buf][r0][0]);
        }
        #pragma unroll
        for (int c = 0; c < 2; ++c) {
            int r0 = c * 64 + wid * 8;
            GLOAD16(Bbase + (size_t)r0 * N_DEM + k0, &Bs[buf][r0][0]);
        }
    };
    auto compute = [&](int buf) {
        #pragma unroll
        for (int kk = 0; kk < 2; ++kk) {
            const int sx = kk ? sx1 : sx0;
            f16x8 a[4], b[2];
            #pragma unroll
            for (int m = 0; m < 4; ++m) a[m] = *(const f16x8*)&As[buf][wr * 64 + m * 16 + cl][sx];
            #pragma unroll
            for (int n = 0; n < 2; ++n) b[n] = *(const f16x8*)&Bs[buf][wc * 32 + n * 16 + cl][sx];
            #pragma unroll
            for (int m = 0; m < 4; ++m)
                #pragma unroll
                for (int n = 0; n < 2; ++n)
                    acc[m][n] = __builtin_amdgcn_mfma_f32_16x16x32_f16(a[m], b[n], acc[m][n], 0, 0, 0);
        }
    };

    int cur = 0;
    stage(0, 0);
    #pragma unroll 1
    for (int k = 0; k < 3; ++k) {
        stage(cur ^ 1, (k + 1) * 64);
        WAITN(4); SBAR();
        compute(cur);
        FENCE(); SBAR();
        cur ^= 1;
    }
    WAITN(0); SBAR();
    compute(cur);

    float lKc2[2], sup2[2]; int pcol[2];
    #pragma unroll
    for (int n = 0; n < 2; ++n) {
        pcol[n] = p0 + wc * 32 + n * 16 + cl;
        lKc2[n] = lKc[pcol[n]]; sup2[n] = supply[pcol[n]];
    }
    #pragma unroll
    for (int m = 0; m < 4; ++m) {
        #pragma unroll
        for (int reg = 0; reg < 4; ++reg) {
            const int srow = sb + wr * 64 + m * 16 + g * 4 + reg;
            const int idx = leak_id[srow];
            const float nv = net[idx];
            #pragma unroll
            for (int n = 0; n < 2; ++n) {
                float qv = acc[m][n][reg] + nv * (float)G16[(size_t)idx * N_PIPES + pcol[n]];
                float l = __builtin_amdgcn_logf(fabsf(qv));
                float hL = copysignf(__builtin_amdgcn_exp2f(fmaf(1.852f, l, lKc2[n])), qv);
                t16[(size_t)srow * N_PIPES + pcol[n]] = (f16)((sup2[n] - hL) * (1.0f / T_SCALE));
            }
        }
    }
}

// ======================= gemm_res (64x128, 8 waves, dbuf, swizzle) =============
// BM=64, BN=128: LDS 48 KB -> 3 blocks/CU (was 2). Wave = 32s x 32n (2x4 waves).
// accH = t*inv^T (K=1024); accR = D16*P1'^T (K=256); r = accR + nv*G2[idx] - dleak
__global__ __launch_bounds__(512, 6) void gemm_res_mfma(
    const f16* __restrict__ t16, const f16* __restrict__ inv16,
    const f16* __restrict__ D16, const f16* __restrict__ P1p,
    const f16* __restrict__ MT16, const f16* __restrict__ G2_16,
    const int* __restrict__ leak_id, const float* __restrict__ net,
    const float* __restrict__ Cd_p, const float* __restrict__ a_p,
    float scale, float* __restrict__ out)
{
    __shared__ __align__(16) f16 As[2][64][64];    // 16 KB
    __shared__ __align__(16) f16 Bs[2][128][64];   // 32 KB
    const int nwg = gridDim.x * gridDim.y;         // 4 x 256 = 1024
    const int bid = blockIdx.y * gridDim.x + blockIdx.x;
    const int w = (bid & 7) * (nwg >> 3) + (bid >> 3);
    const int bx = w % gridDim.x, by = w / gridDim.x;
    const int n0 = bx * 128, sb = by * 64;
    const int t = threadIdx.x, lane = t & 63, wid = t >> 6;
    const int wr = wid >> 2, wc = wid & 3;         // 2(s) x 4(n) waves
    const int cl = lane & 15, g = lane >> 4;
    const int swrow = lane >> 3;
    const int swcol = ((lane & 7) ^ swrow) * 8;
    const int sx0 = (g ^ (cl & 7)) * 8, sx1 = ((4 + g) ^ (cl & 7)) * 8;

    const f16* HAb = t16   + (size_t)(sb + swrow) * N_PIPES + swcol;
    const f16* HBb = inv16 + (size_t)(n0 + swrow) * N_PIPES + swcol;
    const f16* RAb = D16   + (size_t)(sb + swrow) * N_DEM + swcol;
    const f16* RBb = P1p   + (size_t)(n0 + swrow) * N_DEM + swcol;

    f32x4 accH[2][2] = {}, accR[2][2] = {};

    // stage = 3 gloads/wave: 1 for A (8 rows), 2 for B (2x8 rows)
    auto stageH = [&](int buf, int k0) {
        GLOAD16(HAb + (size_t)(wid * 8) * N_PIPES + k0, &As[buf][wid * 8][0]);
        #pragma unroll
        for (int c = 0; c < 2; ++c) {
            int r0 = c * 64 + wid * 8;
            GLOAD16(HBb + (size_t)r0 * N_PIPES + k0, &Bs[buf][r0][0]);
        }
    };
    auto stageR = [&](int buf, int k0) {
        GLOAD16(RAb + (size_t)(wid * 8) * N_DEM + k0, &As[buf][wid * 8][0]);
        #pragma unroll
        for (int c = 0; c < 2; ++c) {
            int r0 = c * 64 + wid * 8;
            GLOAD16(RBb + (size_t)r0 * N_DEM + k0, &Bs[buf][r0][0]);
        }
    };
    auto computeT = [&](int buf, f32x4 (&accA)[2][2]) {
        #pragma unroll
        for (int kk = 0; kk < 2; ++kk) {
            const int sx = kk ? sx1 : sx0;
            f16x8 a[2], b[2];
            #pragma unroll
            for (int m = 0; m < 2; ++m) a[m] = *(const f16x8*)&As[buf][wr * 32 + m * 16 + cl][sx];
            #pragma unroll
            for (int n = 0; n < 2; ++n) b[n] = *(const f16x8*)&Bs[buf][wc * 32 + n * 16 + cl][sx];
            #pragma unroll
            for (int m = 0; m < 2; ++m)
                #pragma unroll
                for (int n = 0; n < 2; ++n)
                    accA[m][n] = __builtin_amdgcn_mfma_f32_16x16x32_f16(a[m], b[n], accA[m][n], 0, 0, 0);
        }
    };

    int cur = 0;
    stageH(0, 0);
    #pragma unroll 1
    for (int k = 0; k < 15; ++k) {
        stageH(cur ^ 1, (k + 1) * 64);
        WAITN(3); SBAR();
        computeT(cur, accH);
        FENCE(); SBAR();
        cur ^= 1;
    }
    // last H iter: prefetch first R tile into the other buffer
    stageR(cur ^ 1, 0);
    WAITN(3); SBAR();
    computeT(cur, accH);
    FENCE(); SBAR();
    cur ^= 1;
    #pragma unroll 1
    for (int k = 0; k < 3; ++k) {
        stageR(cur ^ 1, (k + 1) * 64);
        WAITN(3); SBAR();
        computeT(cur, accR);
        FENCE(); SBAR();
        cur ^= 1;
    }
    WAITN(0); SBAR();
    computeT(cur, accR);

    const float cda = Cd_p[0] * a_p[0] * sqrtf(2.f * 9.80665f);
    int node[2];
    #pragma unroll
    for (int n = 0; n < 2; ++n) node[n] = n0 + wc * 32 + n * 16 + cl;
    float lsum = 0.f;
    #pragma unroll
    for (int m = 0; m < 2; ++m) {
        #pragma unroll
        for (int reg = 0; reg < 4; ++reg) {
            const int srow = sb + wr * 32 + m * 16 + g * 4 + reg;
            const int idx = leak_id[srow];
            const float nv = net[idx];
            #pragma unroll
            for (int n = 0; n < 2; ++n) {
                const float H = accH[m][n][reg] * T_SCALE;
                const float sq = (H > 0.f) ? sqrtf(H) : 0.f;
                const float dl = cda * (float)MT16[(size_t)idx * N_NODES + node[n]] * sq;
                const float r = accR[m][n][reg] + nv * (float)G2_16[(size_t)idx * N_NODES + node[n]] - dl;
                lsum += r * r;
            }
        }
    }
    #pragma unroll
    for (int off = 32; off > 0; off >>= 1) lsum += __shfl_down(lsum, off, 64);
    __syncthreads();
    float* wred = (float*)&As[0][0][0];
    if (lane == 0) wred[wid] = lsum;
    __syncthreads();
    if (t == 0) {
        float tot = 0.f;
        #pragma unroll
        for (int i = 0; i < 8; ++i) tot += wred[i];
        atomicAdd(out, tot * scale);
    }
}

extern "C" void kernel_launch(void* const* d_in, const int* in_sizes, int n_in,
                              void* d_out, int out_size, void* d_ws, size_t ws_size,
                              hipStream_t stream) {
    const float* D          = (const float*)d_in[0];
    const int*   leak_id    = (const int*)  d_in[1];
    const float* A0         = (const float*)d_in[2];
    const float* inv        = (const float*)d_in[3];
    const float* M          = (const float*)d_in[4];
    const float* supply     = (const float*)d_in[5];
    const float* L          = (const float*)d_in[6];
    const float* dpipe      = (const float*)d_in[7];
    const float* C          = (const float*)d_in[8];
    const float* a_p        = (const float*)d_in[9];
    const float* Cd_p       = (const float*)d_in[10];
    const float* W1         = (const float*)d_in[11];
    const float* b1         = (const float*)d_in[12];
    const float* W2         = (const float*)d_in[13];
    const float* b2         = (const float*)d_in[14];
    const float* W3         = (const float*)d_in[15];
    const float* b3         = (const float*)d_in[16];
    const float* base       = (const float*)d_in[17];
    const int*   demand_idx = (const int*)  d_in[18];

    char* ws = (char*)d_ws;
    size_t off = 0;
    auto carve = [&](size_t bytes) { char* p = ws + off; off += (bytes + 255) & ~(size_t)255; return p; };
    float* net    = (float*)carve(N_PIPES * 4);
    float* lKc    = (float*)carve(N_PIPES * 4);
    f16* inv16  = (f16*)carve((size_t)N_NODES * N_PIPES * 2);
    f16* A016   = (f16*)carve((size_t)N_NODES * N_PIPES * 2);
    f16* MT16   = (f16*)carve((size_t)N_PIPES * N_NODES * 2);
    f16* invT16 = (f16*)carve((size_t)N_PIPES * N_NODES * 2);
    f16* G16    = (f16*)carve((size_t)N_PIPES * N_PIPES * 2);
    f16* G2_16  = (f16*)carve((size_t)N_PIPES * N_NODES * 2);
    f16* Wt     = (f16*)carve((size_t)N_NODES * N_NODES * 2);
    f16* P1p    = (f16*)carve((size_t)N_NODES * N_DEM * 2);
    f16* DI16   = (f16*)carve((size_t)N_DEM * N_PIPES * 2);
    f16* IDXT   = (f16*)carve((size_t)N_PIPES * N_DEM * 2);
    f16* D16    = (f16*)carve((size_t)S_TOTAL * N_DEM * 2);
    f16* t16    = (f16*)carve((size_t)S_TOTAL * N_PIPES * 2);

    // ---- dispatch 1: all prep (also zeroes d_out) ----
    prep_all<<<1280, 256, 0, stream>>>(
        W1, b1, W2, b2, W3, b3, base, L, dpipe, C,
        M, inv, A0, D, demand_idx,
        net, lKc, MT16, invT16, inv16, A016, D16, DI16, IDXT,
        (float*)d_out, out_size);

    // ---- dispatch 2: three independent small GEMMs ----
    GemmP pG16 = {MT16, N_NODES, invT16, N_NODES, G16, N_PIPES, N_NODES, nullptr, 16, 8};
    GemmP pWt  = {A016, N_PIPES, inv16, N_PIPES, Wt, N_NODES, N_PIPES, nullptr, 8, 4};
    GemmP pP1  = {A016, N_PIPES, DI16, N_PIPES, P1p, N_DEM, N_PIPES, demand_idx, 4, 4};
    gemm_small3<<<dim3(16, 8, 3), 256, 0, stream>>>(pG16, pWt, pP1);

    // ---- dispatch 3: qt (1024 blocks) + G2 rider (64 blocks) ----
    gemm_qt_mfma<<<dim3(8, 136), 512, 0, stream>>>(
        D16, leak_id, IDXT, net, G16, lKc, supply, t16, MT16, Wt, G2_16);

    // ---- dispatch 4: res (64x128 tile, 3 blocks/CU) ----
    const float scale = 1.f / ((float)S_TOTAL * (float)N_NODES);
    gemm_res_mfma<<<dim3(N_NODES / 128, S_TOTAL / 64), 512, 0, stream>>>(
        t16, inv16, D16, P1p, MT16, G2_16, leak_id, net, Cd_p, a_p,
        scale, (float*)d_out);
}

// Round 15
// 94.248 us; speedup vs baseline: 1.7268x; 1.1021x over previous
//
#include <hip/hip_runtime.h>
#include <math.h>

typedef _Float16 f16;
typedef _Float16 f16x4 __attribute__((ext_vector_type(4)));
typedef _Float16 f16x8 __attribute__((ext_vector_type(8)));
typedef float f32x4 __attribute__((ext_vector_type(4)));

#define S_TOTAL 16384
#define N_NODES 512
#define N_PIPES 1024
#define N_DEM   256
#define HIDDEN  64
#define T_SCALE 256.0f   // t = (supply - hL)/T_SCALE to fit f16 range; H *= T_SCALE

// direct HBM -> LDS, 16B per lane (wave writes base + lane*16, LINEAR dest)
#define GLOAD16(gsrc, ldst) \
    __builtin_amdgcn_global_load_lds((const __attribute__((address_space(1))) void*)(gsrc), \
                                     (__attribute__((address_space(3))) void*)(ldst), 16, 0, 0)
#define SBAR()  __builtin_amdgcn_s_barrier()
#define FENCE() asm volatile("" ::: "memory")
#define WAITN(n) asm volatile("s_waitcnt vmcnt(" #n ")" ::: "memory")

// ================= fused prep: MLP + transposes + conversions + gathers ========
// blocks [0,256):   MLP (4 waves/block, 1 pipe/wave) + d_out zero (block 0)
// blocks [256,512): transpose M (128) and inv (128) to f16 [C][R]
// blocks [512,1280): grid-stride bulk conversions + gathers
__global__ __launch_bounds__(256) void prep_all(
    const float* __restrict__ W1, const float* __restrict__ b1,
    const float* __restrict__ W2, const float* __restrict__ b2,
    const float* __restrict__ W3, const float* __restrict__ b3,
    const float* __restrict__ base,
    const float* __restrict__ L, const float* __restrict__ dpipe,
    const float* __restrict__ Cw,
    const float* __restrict__ Mf, const float* __restrict__ inv,
    const float* __restrict__ A0, const float* __restrict__ D,
    const int* __restrict__ dmap,
    float* __restrict__ net, float* __restrict__ lKc,
    f16* __restrict__ MT16, f16* __restrict__ invT16,
    f16* __restrict__ inv16, f16* __restrict__ A016, f16* __restrict__ D16,
    f16* __restrict__ DI16, f16* __restrict__ IDXT,
    float* __restrict__ out, int out_size)
{
    __shared__ __align__(16) f16 tile[64][72];
    const int b = blockIdx.x, t = threadIdx.x;
    if (b < 256) {
        if (b == 0) for (int i = t; i < out_size; i += 256) out[i] = 0.f;
        const int wid = t >> 6, k = t & 63;
        const int p = b * 4 + wid;
        const float x = (float)p;
        float h1 = tanhf(x * W1[k] + b1[k]);
        float acc = b2[k];
        #pragma unroll
        for (int j = 0; j < HIDDEN; ++j) {
            float hj = __shfl(h1, j, 64);
            acc = fmaf(hj, W2[j * HIDDEN + k], acc);
        }
        float partial = tanhf(acc) * W3[k];
        #pragma unroll
        for (int off = 32; off > 0; off >>= 1) partial += __shfl_down(partial, off, 64);
        if (k == 0) {
            net[p] = base[p] + partial + b3[0];
            lKc[p] = log2f(10.667f) - 1.852f * log2f(Cw[p]) - 4.871f * log2f(dpipe[p]) + log2f(L[p]);
        }
        return;
    }
    if (b < 512) {
        const int idx = b - 256;
        const float* in = (idx < 128) ? Mf : inv;
        f16* outp = (idx < 128) ? MT16 : invT16;
        const int i2 = idx & 127;
        const int bx = i2 & 15, by = i2 >> 4;
        const int r0 = by * 64, c0 = bx * 64;
        const int lr = t / 16, lc4 = (t % 16) * 4;
        #pragma unroll
        for (int i = 0; i < 4; ++i) {
            int r = lr + i * 16;
            float4 v = *(const float4*)(in + (size_t)(r0 + r) * N_PIPES + c0 + lc4);
            tile[lc4 + 0][r] = (f16)v.x; tile[lc4 + 1][r] = (f16)v.y;
            tile[lc4 + 2][r] = (f16)v.z; tile[lc4 + 3][r] = (f16)v.w;
        }
        __syncthreads();
        const int wrow = t / 4, wc16 = (t % 4) * 16;
        *(f16x8*)(outp + (size_t)(c0 + wrow) * N_NODES + r0 + wc16)     = *(f16x8*)&tile[wrow][wc16];
        *(f16x8*)(outp + (size_t)(c0 + wrow) * N_NODES + r0 + wc16 + 8) = *(f16x8*)&tile[wrow][wc16 + 8];
        return;
    }
    const int tid = (b - 512) * 256 + t;
    const int np = 768 * 256;
    for (int i = tid; i < (N_NODES * N_PIPES) / 4; i += np) {
        float4 v = ((const float4*)inv)[i];
        ((f16x4*)inv16)[i] = (f16x4){(f16)v.x, (f16)v.y, (f16)v.z, (f16)v.w};
        float4 w = ((const float4*)A0)[i];
        ((f16x4*)A016)[i] = (f16x4){(f16)w.x, (f16)w.y, (f16)w.z, (f16)w.w};
    }
    for (int i = tid; i < (S_TOTAL * N_DEM) / 4; i += np) {
        float4 v = ((const float4*)D)[i];
        ((f16x4*)D16)[i] = (f16x4){(f16)v.x, (f16)v.y, (f16)v.z, (f16)v.w};
    }
    for (int i = tid; i < N_DEM * (N_PIPES / 4); i += np) {
        int j = i >> 8, p0 = (i & 255) * 4;
        float4 v = *(const float4*)(inv + (size_t)dmap[j] * N_PIPES + p0);
        *(f16x4*)(DI16 + (size_t)j * N_PIPES + p0) = (f16x4){(f16)v.x, (f16)v.y, (f16)v.z, (f16)v.w};
    }
    for (int i = tid; i < N_PIPES * (N_DEM / 4); i += np) {
        int p = i >> 6, j0 = (i & 63) * 4;
        f16x4 o;
        #pragma unroll
        for (int u = 0; u < 4; ++u)
            o[u] = (f16)inv[(size_t)dmap[j0 + u] * N_PIPES + p];
        *(f16x4*)(IDXT + (size_t)p * N_DEM + j0) = o;
    }
}

// ---------------- small MFMA GEMM body (256 thr): C[i][c] = sum_k A[i][k]*B[c][k]
struct GemmP {
    const f16* A; int lda;
    const f16* B; int ldb;
    f16* C; int ldc;
    int K;
    const int* dmap;
    int gx, gy;
};

__device__ __forceinline__ void gemm_body(const GemmP& P, int bx, int by) {
    __shared__ __align__(16) f16 As[128][72], Bs[64][72];
    const int m0 = by * 128, c0 = bx * 64;
    const int t = threadIdx.x, lane = t & 63, wid = t >> 6;
    const int wr = wid >> 1, wc = wid & 1;
    const int cl = lane & 15, g = lane >> 4;
    const int tr = t >> 3, tc = (t & 7) * 8;
    f32x4 acc[4][2] = {};
    for (int k0 = 0; k0 < P.K; k0 += 64) {
        #pragma unroll
        for (int r = 0; r < 4; ++r) {
            int row = r * 32 + tr;
            *(f16x8*)&As[row][tc] = *(const f16x8*)(P.A + (size_t)(m0 + row) * P.lda + k0 + tc);
        }
        #pragma unroll
        for (int r = 0; r < 2; ++r) {
            int row = r * 32 + tr;
            *(f16x8*)&Bs[row][tc] = *(const f16x8*)(P.B + (size_t)(c0 + row) * P.ldb + k0 + tc);
        }
        __syncthreads();
        #pragma unroll
        for (int kk = 0; kk < 2; ++kk) {
            const int kb = kk * 32 + g * 8;
            f16x8 a[4], bfr[2];
            #pragma unroll
            for (int m = 0; m < 4; ++m) a[m] = *(const f16x8*)&As[wr * 64 + m * 16 + cl][kb];
            #pragma unroll
            for (int n = 0; n < 2; ++n) bfr[n] = *(const f16x8*)&Bs[wc * 32 + n * 16 + cl][kb];
            #pragma unroll
            for (int m = 0; m < 4; ++m)
                #pragma unroll
                for (int n = 0; n < 2; ++n)
                    acc[m][n] = __builtin_amdgcn_mfma_f32_16x16x32_f16(a[m], bfr[n], acc[m][n], 0, 0, 0);
        }
        __syncthreads();
    }
    #pragma unroll
    for (int m = 0; m < 4; ++m)
        #pragma unroll
        for (int reg = 0; reg < 4; ++reg) {
            const int row = m0 + wr * 64 + m * 16 + g * 4 + reg;
            #pragma unroll
            for (int n = 0; n < 2; ++n) {
                const int col = c0 + wc * 32 + n * 16 + cl;
                float v = acc[m][n][reg];
                if (P.dmap && P.dmap[col] == row) v -= 1.0f;
                P.C[(size_t)row * P.ldc + col] = (f16)v;
            }
        }
}

__global__ __launch_bounds__(256) void gemm_small3(GemmP p0, GemmP p1, GemmP p2) {
    const GemmP& P = (blockIdx.z == 0) ? p0 : (blockIdx.z == 1) ? p1 : p2;
    if ((int)blockIdx.x >= P.gx || (int)blockIdx.y >= P.gy) return;
    gemm_body(P, blockIdx.x, blockIdx.y);
}

// ======================= gemm_qt + G2 rider (512 thr) ==========================
// y<128: q[s][p] = D16*IDXT^T + nv*G16[idx]; t = (supply - hL)/T_SCALE
//        (round-10 proven path: gload_lds dbuf both operands, vmcnt(4))
// y>=128: G2[i][c] = sum_k MT16[i][k]*Wt[c][k]  (1024x512, K=512)
__global__ __launch_bounds__(512, 4) void gemm_qt_mfma(
    const f16* __restrict__ D16, const int* __restrict__ leak_id,
    const f16* __restrict__ IDXT, const float* __restrict__ net,
    const f16* __restrict__ G16, const float* __restrict__ lKc,
    const float* __restrict__ supply, f16* __restrict__ t16,
    const f16* __restrict__ MT16, const f16* __restrict__ Wt,
    f16* __restrict__ G2out)
{
    __shared__ __align__(16) f16 As[2][128][64];   // 32 KB
    __shared__ __align__(16) f16 Bs[2][128][64];   // 32 KB
    const int t = threadIdx.x, lane = t & 63, wid = t >> 6;

    if (blockIdx.y >= 128) {     // ---------------- G2 rider ----------------
        f16 (*A2)[72] = (f16(*)[72])&Bs[0][0][0];
        f16 (*B2)[72] = (f16(*)[72])&As[0][0][0];
        const int m0 = ((int)blockIdx.y - 128) * 128, c0 = blockIdx.x * 64;
        const int wr = wid >> 2, wc = wid & 3;
        const int cl = lane & 15, g = lane >> 4;
        f32x4 acc[4] = {};
        for (int k0 = 0; k0 < 512; k0 += 64) {
            {
                int r = t >> 2, c16 = (t & 3) * 16;
                *(f16x8*)&A2[r][c16]     = *(const f16x8*)(MT16 + (size_t)(m0 + r) * N_NODES + k0 + c16);
                *(f16x8*)&A2[r][c16 + 8] = *(const f16x8*)(MT16 + (size_t)(m0 + r) * N_NODES + k0 + c16 + 8);
                int r2 = t >> 3, c8 = (t & 7) * 8;
                *(f16x8*)&B2[r2][c8] = *(const f16x8*)(Wt + (size_t)(c0 + r2) * N_NODES + k0 + c8);
            }
            __syncthreads();
            #pragma unroll
            for (int kk = 0; kk < 2; ++kk) {
                const int kb = kk * 32 + g * 8;
                f16x8 b = *(const f16x8*)&B2[wc * 16 + cl][kb];
                #pragma unroll
                for (int m = 0; m < 4; ++m) {
                    f16x8 a = *(const f16x8*)&A2[wr * 64 + m * 16 + cl][kb];
                    acc[m] = __builtin_amdgcn_mfma_f32_16x16x32_f16(a, b, acc[m], 0, 0, 0);
                }
            }
            __syncthreads();
        }
        #pragma unroll
        for (int m = 0; m < 4; ++m)
            #pragma unroll
            for (int reg = 0; reg < 4; ++reg)
                G2out[(size_t)(m0 + wr * 64 + m * 16 + g * 4 + reg) * N_NODES + c0 + wc * 16 + cl] = (f16)acc[m][reg];
        return;
    }
    // ---------------- qt tiles (round-10 schedule) ----------------
    const int bid = blockIdx.y * 8 + blockIdx.x;           // 1024 blocks
    const int w = (bid & 7) * 128 + (bid >> 3);            // XCD-contiguous
    const int bx = w & 7, by = w >> 3;
    const int p0 = bx * 128, sb = by * 128;
    const int wr = wid >> 2, wc = wid & 3;                 // 2 x 4 waves
    const int cl = lane & 15, g = lane >> 4;
    const int swrow = lane >> 3;
    const int swcol = ((lane & 7) ^ swrow) * 8;
    const int sx0 = (g ^ (cl & 7)) * 8, sx1 = ((4 + g) ^ (cl & 7)) * 8;

    const f16* Abase = D16 + (size_t)(sb + swrow) * N_DEM + swcol;
    const f16* Bbase = IDXT + (size_t)(p0 + swrow) * N_DEM + swcol;

    f32x4 acc[4][2] = {};
    auto stage = [&](int buf, int k0) {
        #pragma unroll
        for (int c = 0; c < 2; ++c) {
            int r0 = c * 64 + wid * 8;
            GLOAD16(Abase + (size_t)r0 * N_DEM + k0, &As[buf][r0][0]);
        }
        #pragma unroll
        for (int c = 0; c < 2; ++c) {
            int r0 = c * 64 + wid * 8;
            GLOAD16(Bbase + (size_t)r0 * N_DEM + k0, &Bs[buf][r0][0]);
        }
    };
    auto compute = [&](int buf) {
        #pragma unroll
        for (int kk = 0; kk < 2; ++kk) {
            const int sx = kk ? sx1 : sx0;
            f16x8 a[4], b[2];
            #pragma unroll
            for (int m = 0; m < 4; ++m) a[m] = *(const f16x8*)&As[buf][wr * 64 + m * 16 + cl][sx];
            #pragma unroll
            for (int n = 0; n < 2; ++n) b[n] = *(const f16x8*)&Bs[buf][wc * 32 + n * 16 + cl][sx];
            #pragma unroll
            for (int m = 0; m < 4; ++m)
                #pragma unroll
                for (int n = 0; n < 2; ++n)
                    acc[m][n] = __builtin_amdgcn_mfma_f32_16x16x32_f16(a[m], b[n], acc[m][n], 0, 0, 0);
        }
    };

    int cur = 0;
    stage(0, 0);
    #pragma unroll 1
    for (int k = 0; k < 3; ++k) {
        stage(cur ^ 1, (k + 1) * 64);
        WAITN(4); SBAR();
        compute(cur);
        FENCE(); SBAR();
        cur ^= 1;
    }
    WAITN(0); SBAR();
    compute(cur);

    float lKc2[2], sup2[2]; int pcol[2];
    #pragma unroll
    for (int n = 0; n < 2; ++n) {
        pcol[n] = p0 + wc * 32 + n * 16 + cl;
        lKc2[n] = lKc[pcol[n]]; sup2[n] = supply[pcol[n]];
    }
    #pragma unroll
    for (int m = 0; m < 4; ++m) {
        #pragma unroll
        for (int reg = 0; reg < 4; ++reg) {
            const int srow = sb + wr * 64 + m * 16 + g * 4 + reg;
            const int idx = leak_id[srow];
            const float nv = net[idx];
            #pragma unroll
            for (int n = 0; n < 2; ++n) {
                float qv = acc[m][n][reg] + nv * (float)G16[(size_t)idx * N_PIPES + pcol[n]];
                float l = __builtin_amdgcn_logf(fabsf(qv));
                float hL = copysignf(__builtin_amdgcn_exp2f(fmaf(1.852f, l, lKc2[n])), qv);
                t16[(size_t)srow * N_PIPES + pcol[n]] = (f16)((sup2[n] - hL) * (1.0f / T_SCALE));
            }
        }
    }
}

// ======================= gemm_res (128x128, 8 waves, dbuf, swizzle) ============
// accH = t*inv^T (K=1024); accR = D16*P1'^T (K=256); r = accR + nv*G2[idx] - dleak
__global__ __launch_bounds__(512, 4) void gemm_res_mfma(
    const f16* __restrict__ t16, const f16* __restrict__ inv16,
    const f16* __restrict__ D16, const f16* __restrict__ P1p,
    const f16* __restrict__ MT16, const f16* __restrict__ G2_16,
    const int* __restrict__ leak_id, const float* __restrict__ net,
    const float* __restrict__ Cd_p, const float* __restrict__ a_p,
    float scale, float* __restrict__ out)
{
    __shared__ __align__(16) f16 As[2][128][64];
    __shared__ __align__(16) f16 Bs[2][128][64];
    const int nwg = gridDim.x * gridDim.y;
    const int bid = blockIdx.y * gridDim.x + blockIdx.x;
    const int w = (bid & 7) * (nwg >> 3) + (bid >> 3);
    const int bx = w % gridDim.x, by = w / gridDim.x;
    const int n0 = bx * 128, sb = by * 128;
    const int t = threadIdx.x, lane = t & 63, wid = t >> 6;
    const int wr = wid >> 2, wc = wid & 3;
    const int cl = lane & 15, g = lane >> 4;
    const int swrow = lane >> 3;
    const int swcol = ((lane & 7) ^ swrow) * 8;
    const int sx0 = (g ^ (cl & 7)) * 8, sx1 = ((4 + g) ^ (cl & 7)) * 8;

    const f16* HAb = t16   + (size_t)(sb + swrow) * N_PIPES + swcol;
    const f16* HBb = inv16 + (size_t)(n0 + swrow) * N_PIPES + swcol;
    const f16* RAb = D16   + (size_t)(sb + swrow) * N_DEM + swcol;
    const f16* RBb = P1p   + (size_t)(n0 + swrow) * N_DEM + swcol;

    f32x4 accH[4][2] = {}, accR[4][2] = {};

    auto stageH = [&](int buf, int k0) {
        #pragma unroll
        for (int c = 0; c < 2; ++c) {
            int r0 = c * 64 + wid * 8;
            GLOAD16(HAb + (size_t)r0 * N_PIPES + k0, &As[buf][r0][0]);
        }
        #pragma unroll
        for (int c = 0; c < 2; ++c) {
            int r0 = c * 64 + wid * 8;
            GLOAD16(HBb + (size_t)r0 * N_PIPES + k0, &Bs[buf][r0][0]);
        }
    };
    auto stageR = [&](int buf, int k0) {
        #pragma unroll
        for (int c = 0; c < 2; ++c) {
            int r0 = c * 64 + wid * 8;
            GLOAD16(RAb + (size_t)r0 * N_DEM + k0, &As[buf][r0][0]);
        }
        #pragma unroll
        for (int c = 0; c < 2; ++c) {
            int r0 = c * 64 + wid * 8;
            GLOAD16(RBb + (size_t)r0 * N_DEM + k0, &Bs[buf][r0][0]);
        }
    };
    auto computeT = [&](int buf, f32x4 (&accA)[4][2]) {
        #pragma unroll
        for (int kk = 0; kk < 2; ++kk) {
            const int sx = kk ? sx1 : sx0;
            f16x8 a[4], b[2];
            #pragma unroll
            for (int m = 0; m < 4; ++m) a[m] = *(const f16x8*)&As[buf][wr * 64 + m * 16 + cl][sx];
            #pragma unroll
            for (int n = 0; n < 2; ++n) b[n] = *(const f16x8*)&Bs[buf][wc * 32 + n * 16 + cl][sx];
            #pragma unroll
            for (int m = 0; m < 4; ++m)
                #pragma unroll
                for (int n = 0; n < 2; ++n)
                    accA[m][n] = __builtin_amdgcn_mfma_f32_16x16x32_f16(a[m], b[n], accA[m][n], 0, 0, 0);
        }
    };

    int cur = 0;
    stageH(0, 0);
    #pragma unroll 1
    for (int k = 0; k < 15; ++k) {
        stageH(cur ^ 1, (k + 1) * 64);
        WAITN(4); SBAR();
        computeT(cur, accH);
        FENCE(); SBAR();
        cur ^= 1;
    }
    // last H iter: prefetch first R tile into the other buffer
    stageR(cur ^ 1, 0);
    WAITN(4); SBAR();
    computeT(cur, accH);
    FENCE(); SBAR();
    cur ^= 1;
    #pragma unroll 1
    for (int k = 0; k < 3; ++k) {
        stageR(cur ^ 1, (k + 1) * 64);
        WAITN(4); SBAR();
        computeT(cur, accR);
        FENCE(); SBAR();
        cur ^= 1;
    }
    WAITN(0); SBAR();
    computeT(cur, accR);

    const float cda = Cd_p[0] * a_p[0] * sqrtf(2.f * 9.80665f);
    int node[2];
    #pragma unroll
    for (int n = 0; n < 2; ++n) node[n] = n0 + wc * 32 + n * 16 + cl;
    float lsum = 0.f;
    #pragma unroll
    for (int m = 0; m < 4; ++m) {
        #pragma unroll
        for (int reg = 0; reg < 4; ++reg) {
            const int srow = sb + wr * 64 + m * 16 + g * 4 + reg;
            const int idx = leak_id[srow];
            const float nv = net[idx];
            #pragma unroll
            for (int n = 0; n < 2; ++n) {
                const float H = accH[m][n][reg] * T_SCALE;
                const float sq = (H > 0.f) ? sqrtf(H) : 0.f;
                const float dl = cda * (float)MT16[(size_t)idx * N_NODES + node[n]] * sq;
                const float r = accR[m][n][reg] + nv * (float)G2_16[(size_t)idx * N_NODES + node[n]] - dl;
                lsum += r * r;
            }
        }
    }
    #pragma unroll
    for (int off = 32; off > 0; off >>= 1) lsum += __shfl_down(lsum, off, 64);
    __syncthreads();
    float* wred = (float*)&As[0][0][0];
    if (lane == 0) wred[wid] = lsum;
    __syncthreads();
    if (t == 0) {
        float tot = 0.f;
        #pragma unroll
        for (int i = 0; i < 8; ++i) tot += wred[i];
        atomicAdd(out, tot * scale);
    }
}

extern "C" void kernel_launch(void* const* d_in, const int* in_sizes, int n_in,
                              void* d_out, int out_size, void* d_ws, size_t ws_size,
                              hipStream_t stream) {
    const float* D          = (const float*)d_in[0];
    const int*   leak_id    = (const int*)  d_in[1];
    const float* A0         = (const float*)d_in[2];
    const float* inv        = (const float*)d_in[3];
    const float* M          = (const float*)d_in[4];
    const float* supply     = (const float*)d_in[5];
    const float* L          = (const float*)d_in[6];
    const float* dpipe      = (const float*)d_in[7];
    const float* C          = (const float*)d_in[8];
    const float* a_p        = (const float*)d_in[9];
    const float* Cd_p       = (const float*)d_in[10];
    const float* W1         = (const float*)d_in[11];
    const float* b1         = (const float*)d_in[12];
    const float* W2         = (const float*)d_in[13];
    const float* b2         = (const float*)d_in[14];
    const float* W3         = (const float*)d_in[15];
    const float* b3         = (const float*)d_in[16];
    const float* base       = (const float*)d_in[17];
    const int*   demand_idx = (const int*)  d_in[18];

    char* ws = (char*)d_ws;
    size_t off = 0;
    auto carve = [&](size_t bytes) { char* p = ws + off; off += (bytes + 255) & ~(size_t)255; return p; };
    float* net    = (float*)carve(N_PIPES * 4);
    float* lKc    = (float*)carve(N_PIPES * 4);
    f16* inv16  = (f16*)carve((size_t)N_NODES * N_PIPES * 2);
    f16* A016   = (f16*)carve((size_t)N_NODES * N_PIPES * 2);
    f16* MT16   = (f16*)carve((size_t)N_PIPES * N_NODES * 2);
    f16* invT16 = (f16*)carve((size_t)N_PIPES * N_NODES * 2);
    f16* G16    = (f16*)carve((size_t)N_PIPES * N_PIPES * 2);
    f16* G2_16  = (f16*)carve((size_t)N_PIPES * N_NODES * 2);
    f16* Wt     = (f16*)carve((size_t)N_NODES * N_NODES * 2);
    f16* P1p    = (f16*)carve((size_t)N_NODES * N_DEM * 2);
    f16* DI16   = (f16*)carve((size_t)N_DEM * N_PIPES * 2);
    f16* IDXT   = (f16*)carve((size_t)N_PIPES * N_DEM * 2);
    f16* D16    = (f16*)carve((size_t)S_TOTAL * N_DEM * 2);
    f16* t16    = (f16*)carve((size_t)S_TOTAL * N_PIPES * 2);

    // ---- dispatch 1: all prep (also zeroes d_out) ----
    prep_all<<<1280, 256, 0, stream>>>(
        W1, b1, W2, b2, W3, b3, base, L, dpipe, C,
        M, inv, A0, D, demand_idx,
        net, lKc, MT16, invT16, inv16, A016, D16, DI16, IDXT,
        (float*)d_out, out_size);

    // ---- dispatch 2: three independent small GEMMs ----
    GemmP pG16 = {MT16, N_NODES, invT16, N_NODES, G16, N_PIPES, N_NODES, nullptr, 16, 8};
    GemmP pWt  = {A016, N_PIPES, inv16, N_PIPES, Wt, N_NODES, N_PIPES, nullptr, 8, 4};
    GemmP pP1  = {A016, N_PIPES, DI16, N_PIPES, P1p, N_DEM, N_PIPES, demand_idx, 4, 4};
    gemm_small3<<<dim3(16, 8, 3), 256, 0, stream>>>(pG16, pWt, pP1);

    // ---- dispatch 3: qt (1024 blocks) + G2 rider (64 blocks) ----
    gemm_qt_mfma<<<dim3(8, 136), 512, 0, stream>>>(
        D16, leak_id, IDXT, net, G16, lKc, supply, t16, MT16, Wt, G2_16);

    // ---- dispatch 4: res ----
    const float scale = 1.f / ((float)S_TOTAL * (float)N_NODES);
    gemm_res_mfma<<<dim3(N_NODES / 128, S_TOTAL / 128), 512, 0, stream>>>(
        t16, inv16, D16, P1p, MT16, G2_16, leak_id, net, Cd_p, a_p,
        scale, (float*)d_out);
}

// Round 16
// 89.585 us; speedup vs baseline: 1.8167x; 1.0520x over previous
//
#include <hip/hip_runtime.h>
#include <math.h>

typedef _Float16 f16;
typedef _Float16 f16x4 __attribute__((ext_vector_type(4)));
typedef _Float16 f16x8 __attribute__((ext_vector_type(8)));
typedef float f32x4 __attribute__((ext_vector_type(4)));

#define S_TOTAL 16384
#define N_NODES 512
#define N_PIPES 1024
#define N_DEM   256
#define HIDDEN  64
#define T_SCALE 256.0f   // t = (supply - hL)/T_SCALE; H *= T_SCALE

// direct HBM -> LDS, 16B per lane (wave writes base + lane*16, LINEAR dest)
#define GLOAD16(gsrc, ldst) \
    __builtin_amdgcn_global_load_lds((const __attribute__((address_space(1))) void*)(gsrc), \
                                     (__attribute__((address_space(3))) void*)(ldst), 16, 0, 0)
#define SBAR()  __builtin_amdgcn_s_barrier()
#define FENCE() asm volatile("" ::: "memory")
#define WAITN(n) asm volatile("s_waitcnt vmcnt(" #n ")" ::: "memory")

// f32 -> fp8 e5m2 (bf8): RNE to high byte of f16 bit pattern
__device__ __forceinline__ unsigned char f32_to_bf8(float x) {
    unsigned short h = __builtin_bit_cast(unsigned short, (f16)x);
    unsigned short r = (unsigned short)(h + 0x7F + ((h >> 8) & 1));
    return (unsigned char)(r >> 8);
}

// ================= fused prep: MLP + transposes + conversions + gathers ========
__global__ __launch_bounds__(256) void prep_all(
    const float* __restrict__ W1, const float* __restrict__ b1,
    const float* __restrict__ W2, const float* __restrict__ b2,
    const float* __restrict__ W3, const float* __restrict__ b3,
    const float* __restrict__ base,
    const float* __restrict__ L, const float* __restrict__ dpipe,
    const float* __restrict__ Cw,
    const float* __restrict__ Mf, const float* __restrict__ inv,
    const float* __restrict__ A0, const float* __restrict__ D,
    const int* __restrict__ dmap,
    float* __restrict__ net, float* __restrict__ lKc,
    f16* __restrict__ MT16, f16* __restrict__ invT16,
    f16* __restrict__ inv16, unsigned char* __restrict__ inv8,
    f16* __restrict__ A016, f16* __restrict__ D16,
    f16* __restrict__ DI16, f16* __restrict__ IDXT,
    float* __restrict__ out, int out_size)
{
    __shared__ __align__(16) f16 tile[64][72];
    const int b = blockIdx.x, t = threadIdx.x;
    if (b < 256) {
        if (b == 0) for (int i = t; i < out_size; i += 256) out[i] = 0.f;
        const int wid = t >> 6, k = t & 63;
        const int p = b * 4 + wid;
        const float x = (float)p;
        float h1 = tanhf(x * W1[k] + b1[k]);
        float acc = b2[k];
        #pragma unroll
        for (int j = 0; j < HIDDEN; ++j) {
            float hj = __shfl(h1, j, 64);
            acc = fmaf(hj, W2[j * HIDDEN + k], acc);
        }
        float partial = tanhf(acc) * W3[k];
        #pragma unroll
        for (int off = 32; off > 0; off >>= 1) partial += __shfl_down(partial, off, 64);
        if (k == 0) {
            net[p] = base[p] + partial + b3[0];
            lKc[p] = log2f(10.667f) - 1.852f * log2f(Cw[p]) - 4.871f * log2f(dpipe[p]) + log2f(L[p]);
        }
        return;
    }
    if (b < 512) {
        const int idx = b - 256;
        const float* in = (idx < 128) ? Mf : inv;
        f16* outp = (idx < 128) ? MT16 : invT16;
        const int i2 = idx & 127;
        const int bx = i2 & 15, by = i2 >> 4;
        const int r0 = by * 64, c0 = bx * 64;
        const int lr = t / 16, lc4 = (t % 16) * 4;
        #pragma unroll
        for (int i = 0; i < 4; ++i) {
            int r = lr + i * 16;
            float4 v = *(const float4*)(in + (size_t)(r0 + r) * N_PIPES + c0 + lc4);
            tile[lc4 + 0][r] = (f16)v.x; tile[lc4 + 1][r] = (f16)v.y;
            tile[lc4 + 2][r] = (f16)v.z; tile[lc4 + 3][r] = (f16)v.w;
        }
        __syncthreads();
        const int wrow = t / 4, wc16 = (t % 4) * 16;
        *(f16x8*)(outp + (size_t)(c0 + wrow) * N_NODES + r0 + wc16)     = *(f16x8*)&tile[wrow][wc16];
        *(f16x8*)(outp + (size_t)(c0 + wrow) * N_NODES + r0 + wc16 + 8) = *(f16x8*)&tile[wrow][wc16 + 8];
        return;
    }
    const int tid = (b - 512) * 256 + t;
    const int np = 768 * 256;
    for (int i = tid; i < (N_NODES * N_PIPES) / 4; i += np) {
        float4 v = ((const float4*)inv)[i];
        ((f16x4*)inv16)[i] = (f16x4){(f16)v.x, (f16)v.y, (f16)v.z, (f16)v.w};
        uchar4 v8 = {f32_to_bf8(v.x), f32_to_bf8(v.y), f32_to_bf8(v.z), f32_to_bf8(v.w)};
        ((uchar4*)inv8)[i] = v8;
        float4 w = ((const float4*)A0)[i];
        ((f16x4*)A016)[i] = (f16x4){(f16)w.x, (f16)w.y, (f16)w.z, (f16)w.w};
    }
    for (int i = tid; i < (S_TOTAL * N_DEM) / 4; i += np) {
        float4 v = ((const float4*)D)[i];
        ((f16x4*)D16)[i] = (f16x4){(f16)v.x, (f16)v.y, (f16)v.z, (f16)v.w};
    }
    for (int i = tid; i < N_DEM * (N_PIPES / 4); i += np) {
        int j = i >> 8, p0 = (i & 255) * 4;
        float4 v = *(const float4*)(inv + (size_t)dmap[j] * N_PIPES + p0);
        *(f16x4*)(DI16 + (size_t)j * N_PIPES + p0) = (f16x4){(f16)v.x, (f16)v.y, (f16)v.z, (f16)v.w};
    }
    for (int i = tid; i < N_PIPES * (N_DEM / 4); i += np) {
        int p = i >> 6, j0 = (i & 63) * 4;
        f16x4 o;
        #pragma unroll
        for (int u = 0; u < 4; ++u)
            o[u] = (f16)inv[(size_t)dmap[j0 + u] * N_PIPES + p];
        *(f16x4*)(IDXT + (size_t)p * N_DEM + j0) = o;
    }
}

// ---------------- small MFMA GEMM body (256 thr): C[i][c] = sum_k A[i][k]*B[c][k]
struct GemmP {
    const f16* A; int lda;
    const f16* B; int ldb;
    f16* C; int ldc;
    int K;
    const int* dmap;
    int gx, gy;
};

__device__ __forceinline__ void gemm_body(const GemmP& P, int bx, int by) {
    __shared__ __align__(16) f16 As[128][72], Bs[64][72];
    const int m0 = by * 128, c0 = bx * 64;
    const int t = threadIdx.x, lane = t & 63, wid = t >> 6;
    const int wr = wid >> 1, wc = wid & 1;
    const int cl = lane & 15, g = lane >> 4;
    const int tr = t >> 3, tc = (t & 7) * 8;
    f32x4 acc[4][2] = {};
    for (int k0 = 0; k0 < P.K; k0 += 64) {
        #pragma unroll
        for (int r = 0; r < 4; ++r) {
            int row = r * 32 + tr;
            *(f16x8*)&As[row][tc] = *(const f16x8*)(P.A + (size_t)(m0 + row) * P.lda + k0 + tc);
        }
        #pragma unroll
        for (int r = 0; r < 2; ++r) {
            int row = r * 32 + tr;
            *(f16x8*)&Bs[row][tc] = *(const f16x8*)(P.B + (size_t)(c0 + row) * P.ldb + k0 + tc);
        }
        __syncthreads();
        #pragma unroll
        for (int kk = 0; kk < 2; ++kk) {
            const int kb = kk * 32 + g * 8;
            f16x8 a[4], bfr[2];
            #pragma unroll
            for (int m = 0; m < 4; ++m) a[m] = *(const f16x8*)&As[wr * 64 + m * 16 + cl][kb];
            #pragma unroll
            for (int n = 0; n < 2; ++n) bfr[n] = *(const f16x8*)&Bs[wc * 32 + n * 16 + cl][kb];
            #pragma unroll
            for (int m = 0; m < 4; ++m)
                #pragma unroll
                for (int n = 0; n < 2; ++n)
                    acc[m][n] = __builtin_amdgcn_mfma_f32_16x16x32_f16(a[m], bfr[n], acc[m][n], 0, 0, 0);
        }
        __syncthreads();
    }
    #pragma unroll
    for (int m = 0; m < 4; ++m)
        #pragma unroll
        for (int reg = 0; reg < 4; ++reg) {
            const int row = m0 + wr * 64 + m * 16 + g * 4 + reg;
            #pragma unroll
            for (int n = 0; n < 2; ++n) {
                const int col = c0 + wc * 32 + n * 16 + cl;
                float v = acc[m][n][reg];
                if (P.dmap && P.dmap[col] == row) v -= 1.0f;
                P.C[(size_t)row * P.ldc + col] = (f16)v;
            }
        }
}

__global__ __launch_bounds__(256) void gemm_small3(GemmP p0, GemmP p1, GemmP p2) {
    const GemmP& P = (blockIdx.z == 0) ? p0 : (blockIdx.z == 1) ? p1 : p2;
    if ((int)blockIdx.x >= P.gx || (int)blockIdx.y >= P.gy) return;
    gemm_body(P, blockIdx.x, blockIdx.y);
}

// ======================= gemm_qt + G2 rider (512 thr) ==========================
// y<128: q[s][p] = D16*IDXT^T + nv*G16[idx]; t8 = bf8((supply - hL)/T_SCALE)
// y>=128: G2[i][c] = sum_k MT16[i][k]*Wt[c][k]  (1024x512, K=512)
__global__ __launch_bounds__(512, 4) void gemm_qt_mfma(
    const f16* __restrict__ D16, const int* __restrict__ leak_id,
    const f16* __restrict__ IDXT, const float* __restrict__ net,
    const f16* __restrict__ G16, const float* __restrict__ lKc,
    const float* __restrict__ supply, unsigned char* __restrict__ t8,
    const f16* __restrict__ MT16, const f16* __restrict__ Wt,
    f16* __restrict__ G2out)
{
    __shared__ __align__(16) f16 As[2][128][64];   // 32 KB
    __shared__ __align__(16) f16 Bs[2][128][64];   // 32 KB
    const int t = threadIdx.x, lane = t & 63, wid = t >> 6;

    if (blockIdx.y >= 128) {     // ---------------- G2 rider ----------------
        f16 (*A2)[72] = (f16(*)[72])&Bs[0][0][0];
        f16 (*B2)[72] = (f16(*)[72])&As[0][0][0];
        const int m0 = ((int)blockIdx.y - 128) * 128, c0 = blockIdx.x * 64;
        const int wr = wid >> 2, wc = wid & 3;
        const int cl = lane & 15, g = lane >> 4;
        f32x4 acc[4] = {};
        for (int k0 = 0; k0 < 512; k0 += 64) {
            {
                int r = t >> 2, c16 = (t & 3) * 16;
                *(f16x8*)&A2[r][c16]     = *(const f16x8*)(MT16 + (size_t)(m0 + r) * N_NODES + k0 + c16);
                *(f16x8*)&A2[r][c16 + 8] = *(const f16x8*)(MT16 + (size_t)(m0 + r) * N_NODES + k0 + c16 + 8);
                int r2 = t >> 3, c8 = (t & 7) * 8;
                *(f16x8*)&B2[r2][c8] = *(const f16x8*)(Wt + (size_t)(c0 + r2) * N_NODES + k0 + c8);
            }
            __syncthreads();
            #pragma unroll
            for (int kk = 0; kk < 2; ++kk) {
                const int kb = kk * 32 + g * 8;
                f16x8 b = *(const f16x8*)&B2[wc * 16 + cl][kb];
                #pragma unroll
                for (int m = 0; m < 4; ++m) {
                    f16x8 a = *(const f16x8*)&A2[wr * 64 + m * 16 + cl][kb];
                    acc[m] = __builtin_amdgcn_mfma_f32_16x16x32_f16(a, b, acc[m], 0, 0, 0);
                }
            }
            __syncthreads();
        }
        #pragma unroll
        for (int m = 0; m < 4; ++m)
            #pragma unroll
            for (int reg = 0; reg < 4; ++reg)
                G2out[(size_t)(m0 + wr * 64 + m * 16 + g * 4 + reg) * N_NODES + c0 + wc * 16 + cl] = (f16)acc[m][reg];
        return;
    }
    // ---------------- qt tiles (round-10 schedule) ----------------
    const int bid = blockIdx.y * 8 + blockIdx.x;           // 1024 blocks
    const int w = (bid & 7) * 128 + (bid >> 3);            // XCD-contiguous
    const int bx = w & 7, by = w >> 3;
    const int p0 = bx * 128, sb = by * 128;
    const int wr = wid >> 2, wc = wid & 3;                 // 2 x 4 waves
    const int cl = lane & 15, g = lane >> 4;
    const int swrow = lane >> 3;
    const int swcol = ((lane & 7) ^ swrow) * 8;
    const int sx0 = (g ^ (cl & 7)) * 8, sx1 = ((4 + g) ^ (cl & 7)) * 8;

    const f16* Abase = D16 + (size_t)(sb + swrow) * N_DEM + swcol;
    const f16* Bbase = IDXT + (size_t)(p0 + swrow) * N_DEM + swcol;

    f32x4 acc[4][2] = {};
    auto stage = [&](int buf, int k0) {
        #pragma unroll
        for (int c = 0; c < 2; ++c) {
            int r0 = c * 64 + wid * 8;
            GLOAD16(Abase + (size_t)r0 * N_DEM + k0, &As[buf][r0][0]);
        }
        #pragma unroll
        for (int c = 0; c < 2; ++c) {
            int r0 = c * 64 + wid * 8;
            GLOAD16(Bbase + (size_t)r0 * N_DEM + k0, &Bs[buf][r0][0]);
        }
    };
    auto compute = [&](int buf) {
        #pragma unroll
        for (int kk = 0; kk < 2; ++kk) {
            const int sx = kk ? sx1 : sx0;
            f16x8 a[4], b[2];
            #pragma unroll
            for (int m = 0; m < 4; ++m) a[m] = *(const f16x8*)&As[buf][wr * 64 + m * 16 + cl][sx];
            #pragma unroll
            for (int n = 0; n < 2; ++n) b[n] = *(const f16x8*)&Bs[buf][wc * 32 + n * 16 + cl][sx];
            #pragma unroll
            for (int m = 0; m < 4; ++m)
                #pragma unroll
                for (int n = 0; n < 2; ++n)
                    acc[m][n] = __builtin_amdgcn_mfma_f32_16x16x32_f16(a[m], b[n], acc[m][n], 0, 0, 0);
        }
    };

    int cur = 0;
    stage(0, 0);
    #pragma unroll 1
    for (int k = 0; k < 3; ++k) {
        stage(cur ^ 1, (k + 1) * 64);
        WAITN(4); SBAR();
        compute(cur);
        FENCE(); SBAR();
        cur ^= 1;
    }
    WAITN(0); SBAR();
    compute(cur);

    float lKc2[2], sup2[2]; int pcol[2];
    #pragma unroll
    for (int n = 0; n < 2; ++n) {
        pcol[n] = p0 + wc * 32 + n * 16 + cl;
        lKc2[n] = lKc[pcol[n]]; sup2[n] = supply[pcol[n]];
    }
    #pragma unroll
    for (int m = 0; m < 4; ++m) {
        #pragma unroll
        for (int reg = 0; reg < 4; ++reg) {
            const int srow = sb + wr * 64 + m * 16 + g * 4 + reg;
            const int idx = leak_id[srow];
            const float nv = net[idx];
            #pragma unroll
            for (int n = 0; n < 2; ++n) {
                float qv = acc[m][n][reg] + nv * (float)G16[(size_t)idx * N_PIPES + pcol[n]];
                float l = __builtin_amdgcn_logf(fabsf(qv));
                float hL = copysignf(__builtin_amdgcn_exp2f(fmaf(1.852f, l, lKc2[n])), qv);
                t8[(size_t)srow * N_PIPES + pcol[n]] = f32_to_bf8((sup2[n] - hL) * (1.0f / T_SCALE));
            }
        }
    }
}

// ======================= gemm_res (128x128, 8 waves, dbuf, swizzle) ============
// accH = t8*inv8^T (K=1024, bf8 MFMA, BK=128); accR = D16*P1'^T (K=256, f16)
// LDS unioned: each buffer slot = 16 KB in both phases (128B rows).
__global__ __launch_bounds__(512, 4) void gemm_res_mfma(
    const unsigned char* __restrict__ t8, const unsigned char* __restrict__ inv8,
    const f16* __restrict__ D16, const f16* __restrict__ P1p,
    const f16* __restrict__ MT16, const f16* __restrict__ G2_16,
    const int* __restrict__ leak_id, const float* __restrict__ net,
    const float* __restrict__ Cd_p, const float* __restrict__ a_p,
    float scale, float* __restrict__ out)
{
    __shared__ __align__(16) unsigned char AsM[2][128 * 128];  // 32 KB
    __shared__ __align__(16) unsigned char BsM[2][128 * 128];  // 32 KB
    const int nwg = gridDim.x * gridDim.y;
    const int bid = blockIdx.y * gridDim.x + blockIdx.x;
    const int w = (bid & 7) * (nwg >> 3) + (bid >> 3);
    const int bx = w % gridDim.x, by = w / gridDim.x;
    const int n0 = bx * 128, sb = by * 128;
    const int t = threadIdx.x, lane = t & 63, wid = t >> 6;
    const int wr = wid >> 2, wc = wid & 3;
    const int cl = lane & 15, g = lane >> 4;
    const int swrow = lane >> 3;
    const int swb = ((lane & 7) ^ swrow) * 16;     // byte swizzle, 16B granule

    // H-phase bases (fp8, row stride = N_PIPES bytes)
    const unsigned char* HAb = t8   + (size_t)(sb + swrow) * N_PIPES + swb;
    const unsigned char* HBb = inv8 + (size_t)(n0 + swrow) * N_PIPES + swb;
    // R-phase bases (f16, row stride = N_DEM elements = 512 B)
    const f16* RAb = D16 + (size_t)(sb + swrow) * N_DEM + swb / 2;
    const f16* RBb = P1p + (size_t)(n0 + swrow) * N_DEM + swb / 2;

    f32x4 accH[4][2] = {}, accR[4][2] = {};

    // ---- H staging: BK=128 fp8 bytes/row; 16 rows per wave (2 gloads each side)
    auto stageH = [&](int buf, int k0) {
        #pragma unroll
        for (int c = 0; c < 2; ++c) {
            int r0 = wid * 16 + c * 8;
            GLOAD16(HAb + (size_t)r0 * N_PIPES + k0, &AsM[buf][r0 * 128]);
        }
        #pragma unroll
        for (int c = 0; c < 2; ++c) {
            int r0 = wid * 16 + c * 8;
            GLOAD16(HBb + (size_t)r0 * N_PIPES + k0, &BsM[buf][r0 * 128]);
        }
    };
    auto computeH = [&](int buf) {
        #pragma unroll
        for (int ks = 0; ks < 4; ++ks) {
            const int bo = (ks * 32 + g * 8) ^ ((cl & 7) << 4);
            long long a[4], b[2];
            #pragma unroll
            for (int m = 0; m < 4; ++m)
                a[m] = *(const long long*)&AsM[buf][(wr * 64 + m * 16 + cl) * 128 + bo];
            #pragma unroll
            for (int n = 0; n < 2; ++n)
                b[n] = *(const long long*)&BsM[buf][(wc * 32 + n * 16 + cl) * 128 + bo];
            #pragma unroll
            for (int m = 0; m < 4; ++m)
                #pragma unroll
                for (int n = 0; n < 2; ++n)
                    accH[m][n] = __builtin_amdgcn_mfma_f32_16x16x32_bf8_bf8(a[m], b[n], accH[m][n], 0, 0, 0);
        }
    };

    // ---- R staging: f16, BK=64 elements (128B rows) — same byte geometry
    f16 (*AsF)[128 * 64] = (f16(*)[128 * 64])AsM;   // view: [2][128*64] f16
    f16 (*BsF)[128 * 64] = (f16(*)[128 * 64])BsM;
    auto stageR = [&](int buf, int k0) {
        #pragma unroll
        for (int c = 0; c < 2; ++c) {
            int r0 = c * 64 + wid * 8;
            GLOAD16(RAb + (size_t)r0 * N_DEM + k0, &AsF[buf][r0 * 64]);
        }
        #pragma unroll
        for (int c = 0; c < 2; ++c) {
            int r0 = c * 64 + wid * 8;
            GLOAD16(RBb + (size_t)r0 * N_DEM + k0, &BsF[buf][r0 * 64]);
        }
    };
    const int sx0 = (g ^ (cl & 7)) * 8, sx1 = ((4 + g) ^ (cl & 7)) * 8;
    auto computeR = [&](int buf) {
        #pragma unroll
        for (int kk = 0; kk < 2; ++kk) {
            const int sx = kk ? sx1 : sx0;
            f16x8 a[4], b[2];
            #pragma unroll
            for (int m = 0; m < 4; ++m) a[m] = *(const f16x8*)&AsF[buf][(wr * 64 + m * 16 + cl) * 64 + sx];
            #pragma unroll
            for (int n = 0; n < 2; ++n) b[n] = *(const f16x8*)&BsF[buf][(wc * 32 + n * 16 + cl) * 64 + sx];
            #pragma unroll
            for (int m = 0; m < 4; ++m)
                #pragma unroll
                for (int n = 0; n < 2; ++n)
                    accR[m][n] = __builtin_amdgcn_mfma_f32_16x16x32_f16(a[m], b[n], accR[m][n], 0, 0, 0);
        }
    };

    int cur = 0;
    stageH(0, 0);
    #pragma unroll 1
    for (int k = 0; k < 7; ++k) {
        stageH(cur ^ 1, (k + 1) * 128);
        WAITN(4); SBAR();
        computeH(cur);
        FENCE(); SBAR();
        cur ^= 1;
    }
    // last H iter: prefetch first R tile into the other buffer
    stageR(cur ^ 1, 0);
    WAITN(4); SBAR();
    computeH(cur);
    FENCE(); SBAR();
    cur ^= 1;
    #pragma unroll 1
    for (int k = 0; k < 3; ++k) {
        stageR(cur ^ 1, (k + 1) * 64);
        WAITN(4); SBAR();
        computeR(cur);
        FENCE(); SBAR();
        cur ^= 1;
    }
    WAITN(0); SBAR();
    computeR(cur);

    const float cda = Cd_p[0] * a_p[0] * sqrtf(2.f * 9.80665f);
    int node[2];
    #pragma unroll
    for (int n = 0; n < 2; ++n) node[n] = n0 + wc * 32 + n * 16 + cl;
    float lsum = 0.f;
    #pragma unroll
    for (int m = 0; m < 4; ++m) {
        #pragma unroll
        for (int reg = 0; reg < 4; ++reg) {
            const int srow = sb + wr * 64 + m * 16 + g * 4 + reg;
            const int idx = leak_id[srow];
            const float nv = net[idx];
            #pragma unroll
            for (int n = 0; n < 2; ++n) {
                const float H = accH[m][n][reg] * T_SCALE;
                const float sq = (H > 0.f) ? sqrtf(H) : 0.f;
                const float dl = cda * (float)MT16[(size_t)idx * N_NODES + node[n]] * sq;
                const float r = accR[m][n][reg] + nv * (float)G2_16[(size_t)idx * N_NODES + node[n]] - dl;
                lsum += r * r;
            }
        }
    }
    #pragma unroll
    for (int off = 32; off > 0; off >>= 1) lsum += __shfl_down(lsum, off, 64);
    __syncthreads();
    float* wred = (float*)&AsM[0][0];
    if (lane == 0) wred[wid] = lsum;
    __syncthreads();
    if (t == 0) {
        float tot = 0.f;
        #pragma unroll
        for (int i = 0; i < 8; ++i) tot += wred[i];
        atomicAdd(out, tot * scale);
    }
}

extern "C" void kernel_launch(void* const* d_in, const int* in_sizes, int n_in,
                              void* d_out, int out_size, void* d_ws, size_t ws_size,
                              hipStream_t stream) {
    const float* D          = (const float*)d_in[0];
    const int*   leak_id    = (const int*)  d_in[1];
    const float* A0         = (const float*)d_in[2];
    const float* inv        = (const float*)d_in[3];
    const float* M          = (const float*)d_in[4];
    const float* supply     = (const float*)d_in[5];
    const float* L          = (const float*)d_in[6];
    const float* dpipe      = (const float*)d_in[7];
    const float* C          = (const float*)d_in[8];
    const float* a_p        = (const float*)d_in[9];
    const float* Cd_p       = (const float*)d_in[10];
    const float* W1         = (const float*)d_in[11];
    const float* b1         = (const float*)d_in[12];
    const float* W2         = (const float*)d_in[13];
    const float* b2         = (const float*)d_in[14];
    const float* W3         = (const float*)d_in[15];
    const float* b3         = (const float*)d_in[16];
    const float* base       = (const float*)d_in[17];
    const int*   demand_idx = (const int*)  d_in[18];

    char* ws = (char*)d_ws;
    size_t off = 0;
    auto carve = [&](size_t bytes) { char* p = ws + off; off += (bytes + 255) & ~(size_t)255; return p; };
    float* net    = (float*)carve(N_PIPES * 4);
    float* lKc    = (float*)carve(N_PIPES * 4);
    f16* inv16  = (f16*)carve((size_t)N_NODES * N_PIPES * 2);
    unsigned char* inv8 = (unsigned char*)carve((size_t)N_NODES * N_PIPES);
    f16* A016   = (f16*)carve((size_t)N_NODES * N_PIPES * 2);
    f16* MT16   = (f16*)carve((size_t)N_PIPES * N_NODES * 2);
    f16* invT16 = (f16*)carve((size_t)N_PIPES * N_NODES * 2);
    f16* G16    = (f16*)carve((size_t)N_PIPES * N_PIPES * 2);
    f16* G2_16  = (f16*)carve((size_t)N_PIPES * N_NODES * 2);
    f16* Wt     = (f16*)carve((size_t)N_NODES * N_NODES * 2);
    f16* P1p    = (f16*)carve((size_t)N_NODES * N_DEM * 2);
    f16* DI16   = (f16*)carve((size_t)N_DEM * N_PIPES * 2);
    f16* IDXT   = (f16*)carve((size_t)N_PIPES * N_DEM * 2);
    f16* D16    = (f16*)carve((size_t)S_TOTAL * N_DEM * 2);
    unsigned char* t8 = (unsigned char*)carve((size_t)S_TOTAL * N_PIPES);

    // ---- dispatch 1: all prep (also zeroes d_out) ----
    prep_all<<<1280, 256, 0, stream>>>(
        W1, b1, W2, b2, W3, b3, base, L, dpipe, C,
        M, inv, A0, D, demand_idx,
        net, lKc, MT16, invT16, inv16, inv8, A016, D16, DI16, IDXT,
        (float*)d_out, out_size);

    // ---- dispatch 2: three independent small GEMMs ----
    GemmP pG16 = {MT16, N_NODES, invT16, N_NODES, G16, N_PIPES, N_NODES, nullptr, 16, 8};
    GemmP pWt  = {A016, N_PIPES, inv16, N_PIPES, Wt, N_NODES, N_PIPES, nullptr, 8, 4};
    GemmP pP1  = {A016, N_PIPES, DI16, N_PIPES, P1p, N_DEM, N_PIPES, demand_idx, 4, 4};
    gemm_small3<<<dim3(16, 8, 3), 256, 0, stream>>>(pG16, pWt, pP1);

    // ---- dispatch 3: qt (1024 blocks) + G2 rider (64 blocks) ----
    gemm_qt_mfma<<<dim3(8, 136), 512, 0, stream>>>(
        D16, leak_id, IDXT, net, G16, lKc, supply, t8, MT16, Wt, G2_16);

    // ---- dispatch 4: res (fp8 H-phase) ----
    const float scale = 1.f / ((float)S_TOTAL * (float)N_NODES);
    gemm_res_mfma<<<dim3(N_NODES / 128, S_TOTAL / 128), 512, 0, stream>>>(
        t8, inv8, D16, P1p, MT16, G2_16, leak_id, net, Cd_p, a_p,
        scale, (float*)d_out);
}

// Round 17
// 84.343 us; speedup vs baseline: 1.9296x; 1.0622x over previous
//
#include <hip/hip_runtime.h>
#include <math.h>

typedef _Float16 f16;
typedef _Float16 f16x4 __attribute__((ext_vector_type(4)));
typedef _Float16 f16x8 __attribute__((ext_vector_type(8)));
typedef float f32x4 __attribute__((ext_vector_type(4)));

#define S_TOTAL 16384
#define N_NODES 512
#define N_PIPES 1024
#define N_DEM   256
#define HIDDEN  64
#define T_SCALE 256.0f   // t = (supply - hL)/T_SCALE; H *= T_SCALE

// direct HBM -> LDS, 16B per lane (wave writes base + lane*16, LINEAR dest)
#define GLOAD16(gsrc, ldst) \
    __builtin_amdgcn_global_load_lds((const __attribute__((address_space(1))) void*)(gsrc), \
                                     (__attribute__((address_space(3))) void*)(ldst), 16, 0, 0)
#define SBAR()  __builtin_amdgcn_s_barrier()
#define FENCE() asm volatile("" ::: "memory")
#define WAITN(n) asm volatile("s_waitcnt vmcnt(" #n ")" ::: "memory")

// f32 -> fp8 e5m2 (bf8): RNE to high byte of f16 bit pattern
__device__ __forceinline__ unsigned char f32_to_bf8(float x) {
    unsigned short h = __builtin_bit_cast(unsigned short, (f16)x);
    unsigned short r = (unsigned short)(h + 0x7F + ((h >> 8) & 1));
    return (unsigned char)(r >> 8);
}

// ================= fused prep: MLP + transposes + conversions + gathers ========
__global__ __launch_bounds__(256) void prep_all(
    const float* __restrict__ W1, const float* __restrict__ b1,
    const float* __restrict__ W2, const float* __restrict__ b2,
    const float* __restrict__ W3, const float* __restrict__ b3,
    const float* __restrict__ base,
    const float* __restrict__ L, const float* __restrict__ dpipe,
    const float* __restrict__ Cw,
    const float* __restrict__ Mf, const float* __restrict__ inv,
    const float* __restrict__ A0, const float* __restrict__ D,
    const int* __restrict__ dmap,
    float* __restrict__ net, float* __restrict__ lKc,
    f16* __restrict__ MT16, f16* __restrict__ invT16,
    f16* __restrict__ inv16, unsigned char* __restrict__ inv8,
    f16* __restrict__ A016, unsigned char* __restrict__ D8,
    f16* __restrict__ DI16, unsigned char* __restrict__ IDXT8,
    float* __restrict__ out, int out_size)
{
    __shared__ __align__(16) f16 tile[64][72];
    const int b = blockIdx.x, t = threadIdx.x;
    if (b < 256) {
        if (b == 0) for (int i = t; i < out_size; i += 256) out[i] = 0.f;
        const int wid = t >> 6, k = t & 63;
        const int p = b * 4 + wid;
        const float x = (float)p;
        float h1 = tanhf(x * W1[k] + b1[k]);
        float acc = b2[k];
        #pragma unroll
        for (int j = 0; j < HIDDEN; ++j) {
            float hj = __shfl(h1, j, 64);
            acc = fmaf(hj, W2[j * HIDDEN + k], acc);
        }
        float partial = tanhf(acc) * W3[k];
        #pragma unroll
        for (int off = 32; off > 0; off >>= 1) partial += __shfl_down(partial, off, 64);
        if (k == 0) {
            net[p] = base[p] + partial + b3[0];
            lKc[p] = log2f(10.667f) - 1.852f * log2f(Cw[p]) - 4.871f * log2f(dpipe[p]) + log2f(L[p]);
        }
        return;
    }
    if (b < 512) {
        const int idx = b - 256;
        const float* in = (idx < 128) ? Mf : inv;
        f16* outp = (idx < 128) ? MT16 : invT16;
        const int i2 = idx & 127;
        const int bx = i2 & 15, by = i2 >> 4;
        const int r0 = by * 64, c0 = bx * 64;
        const int lr = t / 16, lc4 = (t % 16) * 4;
        #pragma unroll
        for (int i = 0; i < 4; ++i) {
            int r = lr + i * 16;
            float4 v = *(const float4*)(in + (size_t)(r0 + r) * N_PIPES + c0 + lc4);
            tile[lc4 + 0][r] = (f16)v.x; tile[lc4 + 1][r] = (f16)v.y;
            tile[lc4 + 2][r] = (f16)v.z; tile[lc4 + 3][r] = (f16)v.w;
        }
        __syncthreads();
        const int wrow = t / 4, wc16 = (t % 4) * 16;
        *(f16x8*)(outp + (size_t)(c0 + wrow) * N_NODES + r0 + wc16)     = *(f16x8*)&tile[wrow][wc16];
        *(f16x8*)(outp + (size_t)(c0 + wrow) * N_NODES + r0 + wc16 + 8) = *(f16x8*)&tile[wrow][wc16 + 8];
        return;
    }
    const int tid = (b - 512) * 256 + t;
    const int np = 768 * 256;
    for (int i = tid; i < (N_NODES * N_PIPES) / 4; i += np) {
        float4 v = ((const float4*)inv)[i];
        ((f16x4*)inv16)[i] = (f16x4){(f16)v.x, (f16)v.y, (f16)v.z, (f16)v.w};
        uchar4 v8 = {f32_to_bf8(v.x), f32_to_bf8(v.y), f32_to_bf8(v.z), f32_to_bf8(v.w)};
        ((uchar4*)inv8)[i] = v8;
        float4 w = ((const float4*)A0)[i];
        ((f16x4*)A016)[i] = (f16x4){(f16)w.x, (f16)w.y, (f16)w.z, (f16)w.w};
    }
    for (int i = tid; i < (S_TOTAL * N_DEM) / 4; i += np) {
        float4 v = ((const float4*)D)[i];
        uchar4 o = {f32_to_bf8(v.x), f32_to_bf8(v.y), f32_to_bf8(v.z), f32_to_bf8(v.w)};
        ((uchar4*)D8)[i] = o;
    }
    for (int i = tid; i < N_DEM * (N_PIPES / 4); i += np) {
        int j = i >> 8, p0 = (i & 255) * 4;
        float4 v = *(const float4*)(inv + (size_t)dmap[j] * N_PIPES + p0);
        *(f16x4*)(DI16 + (size_t)j * N_PIPES + p0) = (f16x4){(f16)v.x, (f16)v.y, (f16)v.z, (f16)v.w};
    }
    for (int i = tid; i < N_PIPES * (N_DEM / 4); i += np) {
        int p = i >> 6, j0 = (i & 63) * 4;
        uchar4 o;
        #pragma unroll
        for (int u = 0; u < 4; ++u)
            o[u] = f32_to_bf8(inv[(size_t)dmap[j0 + u] * N_PIPES + p]);
        *(uchar4*)(IDXT8 + (size_t)p * N_DEM + j0) = o;
    }
}

// ---------------- small MFMA GEMM body (256 thr): C[i][c] = sum_k A[i][k]*B[c][k]
struct GemmP {
    const f16* A; int lda;
    const f16* B; int ldb;
    f16* C; int ldc;
    int K;
    const int* dmap;
    int gx, gy;
    unsigned char* C8;   // if non-null, write bf8 here instead of C
};

__device__ __forceinline__ void gemm_body(const GemmP& P, int bx, int by) {
    __shared__ __align__(16) f16 As[128][72], Bs[64][72];
    const int m0 = by * 128, c0 = bx * 64;
    const int t = threadIdx.x, lane = t & 63, wid = t >> 6;
    const int wr = wid >> 1, wc = wid & 1;
    const int cl = lane & 15, g = lane >> 4;
    const int tr = t >> 3, tc = (t & 7) * 8;
    f32x4 acc[4][2] = {};
    for (int k0 = 0; k0 < P.K; k0 += 64) {
        #pragma unroll
        for (int r = 0; r < 4; ++r) {
            int row = r * 32 + tr;
            *(f16x8*)&As[row][tc] = *(const f16x8*)(P.A + (size_t)(m0 + row) * P.lda + k0 + tc);
        }
        #pragma unroll
        for (int r = 0; r < 2; ++r) {
            int row = r * 32 + tr;
            *(f16x8*)&Bs[row][tc] = *(const f16x8*)(P.B + (size_t)(c0 + row) * P.ldb + k0 + tc);
        }
        __syncthreads();
        #pragma unroll
        for (int kk = 0; kk < 2; ++kk) {
            const int kb = kk * 32 + g * 8;
            f16x8 a[4], bfr[2];
            #pragma unroll
            for (int m = 0; m < 4; ++m) a[m] = *(const f16x8*)&As[wr * 64 + m * 16 + cl][kb];
            #pragma unroll
            for (int n = 0; n < 2; ++n) bfr[n] = *(const f16x8*)&Bs[wc * 32 + n * 16 + cl][kb];
            #pragma unroll
            for (int m = 0; m < 4; ++m)
                #pragma unroll
                for (int n = 0; n < 2; ++n)
                    acc[m][n] = __builtin_amdgcn_mfma_f32_16x16x32_f16(a[m], bfr[n], acc[m][n], 0, 0, 0);
        }
        __syncthreads();
    }
    #pragma unroll
    for (int m = 0; m < 4; ++m)
        #pragma unroll
        for (int reg = 0; reg < 4; ++reg) {
            const int row = m0 + wr * 64 + m * 16 + g * 4 + reg;
            #pragma unroll
            for (int n = 0; n < 2; ++n) {
                const int col = c0 + wc * 32 + n * 16 + cl;
                float v = acc[m][n][reg];
                if (P.dmap && P.dmap[col] == row) v -= 1.0f;
                if (P.C8) P.C8[(size_t)row * P.ldc + col] = f32_to_bf8(v);
                else      P.C [(size_t)row * P.ldc + col] = (f16)v;
            }
        }
}

__global__ __launch_bounds__(256) void gemm_small3(GemmP p0, GemmP p1, GemmP p2) {
    const GemmP& P = (blockIdx.z == 0) ? p0 : (blockIdx.z == 1) ? p1 : p2;
    if ((int)blockIdx.x >= P.gx || (int)blockIdx.y >= P.gy) return;
    gemm_body(P, blockIdx.x, blockIdx.y);
}

// ======================= gemm_qt + G2 rider (512 thr) ==========================
// y<128: q[s][p] = D8*IDXT8^T (bf8, BK=128) + nv*G16[idx]; t8 = bf8((supply-hL)/T_SCALE)
// y>=128: G2[i][c] = sum_k MT16[i][k]*Wt[c][k]  (1024x512, K=512, f16)
__global__ __launch_bounds__(512, 4) void gemm_qt_mfma(
    const unsigned char* __restrict__ D8, const int* __restrict__ leak_id,
    const unsigned char* __restrict__ IDXT8, const float* __restrict__ net,
    const f16* __restrict__ G16, const float* __restrict__ lKc,
    const float* __restrict__ supply, unsigned char* __restrict__ t8,
    const f16* __restrict__ MT16, const f16* __restrict__ Wt,
    f16* __restrict__ G2out)
{
    __shared__ __align__(16) unsigned char As[2][128 * 128];   // 32 KB
    __shared__ __align__(16) unsigned char Bs[2][128 * 128];   // 32 KB
    const int t = threadIdx.x, lane = t & 63, wid = t >> 6;

    if (blockIdx.y >= 128) {     // ---------------- G2 rider (f16) ----------------
        f16 (*A2)[72] = (f16(*)[72])&Bs[0][0];
        f16 (*B2)[72] = (f16(*)[72])&As[0][0];
        const int m0 = ((int)blockIdx.y - 128) * 128, c0 = blockIdx.x * 64;
        const int wr = wid >> 2, wc = wid & 3;
        const int cl = lane & 15, g = lane >> 4;
        f32x4 acc[4] = {};
        for (int k0 = 0; k0 < 512; k0 += 64) {
            {
                int r = t >> 2, c16 = (t & 3) * 16;
                *(f16x8*)&A2[r][c16]     = *(const f16x8*)(MT16 + (size_t)(m0 + r) * N_NODES + k0 + c16);
                *(f16x8*)&A2[r][c16 + 8] = *(const f16x8*)(MT16 + (size_t)(m0 + r) * N_NODES + k0 + c16 + 8);
                int r2 = t >> 3, c8 = (t & 7) * 8;
                *(f16x8*)&B2[r2][c8] = *(const f16x8*)(Wt + (size_t)(c0 + r2) * N_NODES + k0 + c8);
            }
            __syncthreads();
            #pragma unroll
            for (int kk = 0; kk < 2; ++kk) {
                const int kb = kk * 32 + g * 8;
                f16x8 b = *(const f16x8*)&B2[wc * 16 + cl][kb];
                #pragma unroll
                for (int m = 0; m < 4; ++m) {
                    f16x8 a = *(const f16x8*)&A2[wr * 64 + m * 16 + cl][kb];
                    acc[m] = __builtin_amdgcn_mfma_f32_16x16x32_f16(a, b, acc[m], 0, 0, 0);
                }
            }
            __syncthreads();
        }
        #pragma unroll
        for (int m = 0; m < 4; ++m)
            #pragma unroll
            for (int reg = 0; reg < 4; ++reg)
                G2out[(size_t)(m0 + wr * 64 + m * 16 + g * 4 + reg) * N_NODES + c0 + wc * 16 + cl] = (f16)acc[m][reg];
        return;
    }
    // ---------------- qt tiles (bf8, BK=128, 2 K-steps) ----------------
    const int bid = blockIdx.y * 8 + blockIdx.x;           // 1024 blocks
    const int w = (bid & 7) * 128 + (bid >> 3);            // XCD-contiguous
    const int bx = w & 7, by = w >> 3;
    const int p0 = bx * 128, sb = by * 128;
    const int wr = wid >> 2, wc = wid & 3;                 // 2 x 4 waves
    const int cl = lane & 15, g = lane >> 4;
    const int swrow = lane >> 3;
    const int swb = ((lane & 7) ^ swrow) * 16;             // 16B-granule byte swizzle

    const unsigned char* Abase = D8    + (size_t)(sb + swrow) * N_DEM + swb;
    const unsigned char* Bbase = IDXT8 + (size_t)(p0 + swrow) * N_DEM + swb;

    f32x4 acc[4][2] = {};
    auto stage = [&](int buf, int k0) {
        #pragma unroll
        for (int c = 0; c < 2; ++c) {
            int r0 = wid * 16 + c * 8;
            GLOAD16(Abase + (size_t)r0 * N_DEM + k0, &As[buf][r0 * 128]);
        }
        #pragma unroll
        for (int c = 0; c < 2; ++c) {
            int r0 = wid * 16 + c * 8;
            GLOAD16(Bbase + (size_t)r0 * N_DEM + k0, &Bs[buf][r0 * 128]);
        }
    };
    auto compute = [&](int buf) {
        #pragma unroll
        for (int ks = 0; ks < 4; ++ks) {
            const int bo = (ks * 32 + g * 8) ^ ((cl & 7) << 4);
            long long a[4], b[2];
            #pragma unroll
            for (int m = 0; m < 4; ++m)
                a[m] = *(const long long*)&As[buf][(wr * 64 + m * 16 + cl) * 128 + bo];
            #pragma unroll
            for (int n = 0; n < 2; ++n)
                b[n] = *(const long long*)&Bs[buf][(wc * 32 + n * 16 + cl) * 128 + bo];
            #pragma unroll
            for (int m = 0; m < 4; ++m)
                #pragma unroll
                for (int n = 0; n < 2; ++n)
                    acc[m][n] = __builtin_amdgcn_mfma_f32_16x16x32_bf8_bf8(a[m], b[n], acc[m][n], 0, 0, 0);
        }
    };

    stage(0, 0);
    stage(1, 128);
    WAITN(4); SBAR();
    compute(0);
    FENCE(); SBAR();
    WAITN(0); SBAR();
    compute(1);

    float lKc2[2], sup2[2]; int pcol[2];
    #pragma unroll
    for (int n = 0; n < 2; ++n) {
        pcol[n] = p0 + wc * 32 + n * 16 + cl;
        lKc2[n] = lKc[pcol[n]]; sup2[n] = supply[pcol[n]];
    }
    #pragma unroll
    for (int m = 0; m < 4; ++m) {
        #pragma unroll
        for (int reg = 0; reg < 4; ++reg) {
            const int srow = sb + wr * 64 + m * 16 + g * 4 + reg;
            const int idx = leak_id[srow];
            const float nv = net[idx];
            #pragma unroll
            for (int n = 0; n < 2; ++n) {
                float qv = acc[m][n][reg] + nv * (float)G16[(size_t)idx * N_PIPES + pcol[n]];
                float l = __builtin_amdgcn_logf(fabsf(qv));
                float hL = copysignf(__builtin_amdgcn_exp2f(fmaf(1.852f, l, lKc2[n])), qv);
                t8[(size_t)srow * N_PIPES + pcol[n]] = f32_to_bf8((sup2[n] - hL) * (1.0f / T_SCALE));
            }
        }
    }
}

// ======================= gemm_res (128x128, 8 waves, dbuf, bf8) ================
// accH = t8*inv8^T (K=1024, bf8, BK=128, 8 steps); accR = D8*P1p8^T (K=256, bf8, 2 steps)
__global__ __launch_bounds__(512, 4) void gemm_res_mfma(
    const unsigned char* __restrict__ t8, const unsigned char* __restrict__ inv8,
    const unsigned char* __restrict__ D8, const unsigned char* __restrict__ P1p8,
    const f16* __restrict__ MT16, const f16* __restrict__ G2_16,
    const int* __restrict__ leak_id, const float* __restrict__ net,
    const float* __restrict__ Cd_p, const float* __restrict__ a_p,
    float scale, float* __restrict__ out)
{
    __shared__ __align__(16) unsigned char AsM[2][128 * 128];  // 32 KB
    __shared__ __align__(16) unsigned char BsM[2][128 * 128];  // 32 KB
    const int nwg = gridDim.x * gridDim.y;
    const int bid = blockIdx.y * gridDim.x + blockIdx.x;
    const int w = (bid & 7) * (nwg >> 3) + (bid >> 3);
    const int bx = w % gridDim.x, by = w / gridDim.x;
    const int n0 = bx * 128, sb = by * 128;
    const int t = threadIdx.x, lane = t & 63, wid = t >> 6;
    const int wr = wid >> 2, wc = wid & 3;
    const int cl = lane & 15, g = lane >> 4;
    const int swrow = lane >> 3;
    const int swb = ((lane & 7) ^ swrow) * 16;     // byte swizzle, 16B granule

    const unsigned char* HAb = t8   + (size_t)(sb + swrow) * N_PIPES + swb;
    const unsigned char* HBb = inv8 + (size_t)(n0 + swrow) * N_PIPES + swb;
    const unsigned char* RAb = D8   + (size_t)(sb + swrow) * N_DEM + swb;
    const unsigned char* RBb = P1p8 + (size_t)(n0 + swrow) * N_DEM + swb;

    f32x4 accH[4][2] = {}, accR[4][2] = {};

    auto stageH = [&](int buf, int k0) {
        #pragma unroll
        for (int c = 0; c < 2; ++c) {
            int r0 = wid * 16 + c * 8;
            GLOAD16(HAb + (size_t)r0 * N_PIPES + k0, &AsM[buf][r0 * 128]);
        }
        #pragma unroll
        for (int c = 0; c < 2; ++c) {
            int r0 = wid * 16 + c * 8;
            GLOAD16(HBb + (size_t)r0 * N_PIPES + k0, &BsM[buf][r0 * 128]);
        }
    };
    auto stageR = [&](int buf, int k0) {
        #pragma unroll
        for (int c = 0; c < 2; ++c) {
            int r0 = wid * 16 + c * 8;
            GLOAD16(RAb + (size_t)r0 * N_DEM + k0, &AsM[buf][r0 * 128]);
        }
        #pragma unroll
        for (int c = 0; c < 2; ++c) {
            int r0 = wid * 16 + c * 8;
            GLOAD16(RBb + (size_t)r0 * N_DEM + k0, &BsM[buf][r0 * 128]);
        }
    };
    auto computeT = [&](int buf, f32x4 (&accA)[4][2]) {
        #pragma unroll
        for (int ks = 0; ks < 4; ++ks) {
            const int bo = (ks * 32 + g * 8) ^ ((cl & 7) << 4);
            long long a[4], b[2];
            #pragma unroll
            for (int m = 0; m < 4; ++m)
                a[m] = *(const long long*)&AsM[buf][(wr * 64 + m * 16 + cl) * 128 + bo];
            #pragma unroll
            for (int n = 0; n < 2; ++n)
                b[n] = *(const long long*)&BsM[buf][(wc * 32 + n * 16 + cl) * 128 + bo];
            #pragma unroll
            for (int m = 0; m < 4; ++m)
                #pragma unroll
                for (int n = 0; n < 2; ++n)
                    accA[m][n] = __builtin_amdgcn_mfma_f32_16x16x32_bf8_bf8(a[m], b[n], accA[m][n], 0, 0, 0);
        }
    };

    int cur = 0;
    stageH(0, 0);
    #pragma unroll 1
    for (int k = 0; k < 7; ++k) {
        stageH(cur ^ 1, (k + 1) * 128);
        WAITN(4); SBAR();
        computeT(cur, accH);
        FENCE(); SBAR();
        cur ^= 1;
    }
    // last H iter: prefetch first R tile into the other buffer
    stageR(cur ^ 1, 0);
    WAITN(4); SBAR();
    computeT(cur, accH);
    FENCE(); SBAR();
    cur ^= 1;
    // R: 2 K-steps (BK=128 of K=256)
    stageR(cur ^ 1, 128);
    WAITN(4); SBAR();
    computeT(cur, accR);
    FENCE(); SBAR();
    cur ^= 1;
    WAITN(0); SBAR();
    computeT(cur, accR);

    const float cda = Cd_p[0] * a_p[0] * sqrtf(2.f * 9.80665f);
    int node[2];
    #pragma unroll
    for (int n = 0; n < 2; ++n) node[n] = n0 + wc * 32 + n * 16 + cl;
    float lsum = 0.f;
    #pragma unroll
    for (int m = 0; m < 4; ++m) {
        #pragma unroll
        for (int reg = 0; reg < 4; ++reg) {
            const int srow = sb + wr * 64 + m * 16 + g * 4 + reg;
            const int idx = leak_id[srow];
            const float nv = net[idx];
            #pragma unroll
            for (int n = 0; n < 2; ++n) {
                const float H = accH[m][n][reg] * T_SCALE;
                const float sq = (H > 0.f) ? sqrtf(H) : 0.f;
                const float dl = cda * (float)MT16[(size_t)idx * N_NODES + node[n]] * sq;
                const float r = accR[m][n][reg] + nv * (float)G2_16[(size_t)idx * N_NODES + node[n]] - dl;
                lsum += r * r;
            }
        }
    }
    #pragma unroll
    for (int off = 32; off > 0; off >>= 1) lsum += __shfl_down(lsum, off, 64);
    __syncthreads();
    float* wred = (float*)&AsM[0][0];
    if (lane == 0) wred[wid] = lsum;
    __syncthreads();
    if (t == 0) {
        float tot = 0.f;
        #pragma unroll
        for (int i = 0; i < 8; ++i) tot += wred[i];
        atomicAdd(out, tot * scale);
    }
}

extern "C" void kernel_launch(void* const* d_in, const int* in_sizes, int n_in,
                              void* d_out, int out_size, void* d_ws, size_t ws_size,
                              hipStream_t stream) {
    const float* D          = (const float*)d_in[0];
    const int*   leak_id    = (const int*)  d_in[1];
    const float* A0         = (const float*)d_in[2];
    const float* inv        = (const float*)d_in[3];
    const float* M          = (const float*)d_in[4];
    const float* supply     = (const float*)d_in[5];
    const float* L          = (const float*)d_in[6];
    const float* dpipe      = (const float*)d_in[7];
    const float* C          = (const float*)d_in[8];
    const float* a_p        = (const float*)d_in[9];
    const float* Cd_p       = (const float*)d_in[10];
    const float* W1         = (const float*)d_in[11];
    const float* b1         = (const float*)d_in[12];
    const float* W2         = (const float*)d_in[13];
    const float* b2         = (const float*)d_in[14];
    const float* W3         = (const float*)d_in[15];
    const float* b3         = (const float*)d_in[16];
    const float* base       = (const float*)d_in[17];
    const int*   demand_idx = (const int*)  d_in[18];

    char* ws = (char*)d_ws;
    size_t off = 0;
    auto carve = [&](size_t bytes) { char* p = ws + off; off += (bytes + 255) & ~(size_t)255; return p; };
    float* net    = (float*)carve(N_PIPES * 4);
    float* lKc    = (float*)carve(N_PIPES * 4);
    f16* inv16  = (f16*)carve((size_t)N_NODES * N_PIPES * 2);
    unsigned char* inv8 = (unsigned char*)carve((size_t)N_NODES * N_PIPES);
    f16* A016   = (f16*)carve((size_t)N_NODES * N_PIPES * 2);
    f16* MT16   = (f16*)carve((size_t)N_PIPES * N_NODES * 2);
    f16* invT16 = (f16*)carve((size_t)N_PIPES * N_NODES * 2);
    f16* G16    = (f16*)carve((size_t)N_PIPES * N_PIPES * 2);
    f16* G2_16  = (f16*)carve((size_t)N_PIPES * N_NODES * 2);
    f16* Wt     = (f16*)carve((size_t)N_NODES * N_NODES * 2);
    unsigned char* P1p8 = (unsigned char*)carve((size_t)N_NODES * N_DEM);
    f16* DI16   = (f16*)carve((size_t)N_DEM * N_PIPES * 2);
    unsigned char* IDXT8 = (unsigned char*)carve((size_t)N_PIPES * N_DEM);
    unsigned char* D8    = (unsigned char*)carve((size_t)S_TOTAL * N_DEM);
    unsigned char* t8    = (unsigned char*)carve((size_t)S_TOTAL * N_PIPES);

    // ---- dispatch 1: all prep (also zeroes d_out) ----
    prep_all<<<1280, 256, 0, stream>>>(
        W1, b1, W2, b2, W3, b3, base, L, dpipe, C,
        M, inv, A0, D, demand_idx,
        net, lKc, MT16, invT16, inv16, inv8, A016, D8, DI16, IDXT8,
        (float*)d_out, out_size);

    // ---- dispatch 2: three independent small GEMMs ----
    GemmP pG16 = {MT16, N_NODES, invT16, N_NODES, G16, N_PIPES, N_NODES, nullptr, 16, 8, nullptr};
    GemmP pWt  = {A016, N_PIPES, inv16, N_PIPES, Wt, N_NODES, N_PIPES, nullptr, 8, 4, nullptr};
    GemmP pP1  = {A016, N_PIPES, DI16, N_PIPES, nullptr, N_DEM, N_PIPES, demand_idx, 4, 4, P1p8};
    gemm_small3<<<dim3(16, 8, 3), 256, 0, stream>>>(pG16, pWt, pP1);

    // ---- dispatch 3: qt (1024 blocks, bf8) + G2 rider (64 blocks) ----
    gemm_qt_mfma<<<dim3(8, 136), 512, 0, stream>>>(
        D8, leak_id, IDXT8, net, G16, lKc, supply, t8, MT16, Wt, G2_16);

    // ---- dispatch 4: res (all-bf8 GEMM phases) ----
    const float scale = 1.f / ((float)S_TOTAL * (float)N_NODES);
    gemm_res_mfma<<<dim3(N_NODES / 128, S_TOTAL / 128), 512, 0, stream>>>(
        t8, inv8, D8, P1p8, MT16, G2_16, leak_id, net, Cd_p, a_p,
        scale, (float*)d_out);
}